// Round 16
// baseline (667.040 us; speedup 1.0000x reference)
//
#include <hip/hip_runtime.h>
#include <math.h>

#define VN 100000
#define DD 128
#define BBATCH 16
#define HH 64
#define NEL (BBATCH*VN)   // 1,600,000
#define NB_STAT 1563      // chunks of 1024
#define NVGRP 196
#define NBLK_SIMS (16*NVGRP)  // 3136, divisible by 8

#define FLAG_CAP 262144u
#define FLAG_EPS 4e-5f

// ---- workspace layout (bytes) ----
#define OFF_CNT    0
#define OFF_TICK   256                          // 3 x u32 phase tickets
#define OFF_FLAG   1024
#define OFF_RNORM  (OFF_FLAG + FLAG_CAP*4)
#define OFF_RQD    (OFF_RNORM + VN*4)
#define OFF_QG     (OFF_RQD + 1024*8)           // QgT (fp32, b x k x h = 512KB)
#define OFF_S      (OFF_QG + 1024*DD*4)
#define OFF_MW     (OFF_S + NEL*4)
#define OFF_PART1  (OFF_MW + NEL*4)             // 1563*16*4
#define OFF_PART2  (OFF_PART1 + NB_STAT*16*4)   // 1563*64*4
#define OFF_PART3  (OFF_PART2 + NB_STAT*64*4)   // 1563*16*4
#define OFF_SCSH1  (OFF_PART3 + NB_STAT*16*4)
#define OFF_SCSH2  (OFF_SCSH1 + 256)
#define OFF_SCSH3  (OFF_SCSH2 + 256)
#define OFF_EMBH   ((size_t)(OFF_SCSH3 + 256))
#define OFF_EMBL   (OFF_EMBH + (size_t)VN*DD*2)
#define OFF_QH     (OFF_EMBL + (size_t)VN*DD*2)
#define OFF_QL     (OFF_QH + (size_t)1024*DD*2)

typedef __attribute__((ext_vector_type(8))) short short8;
typedef __attribute__((ext_vector_type(16))) float f32x16;

__device__ __forceinline__ float leaky1(float x) { return x >= 0.f ? x : 0.01f * x; }

__device__ __forceinline__ unsigned short f2bf(float f) {
    unsigned u = __float_as_uint(f);
    u += 0x7fffu + ((u >> 16) & 1u);
    return (unsigned short)(u >> 16);
}
__device__ __forceinline__ float bf2f(unsigned short s) {
    return __uint_as_float(((unsigned)s) << 16);
}

// ---------------- K1: prep = cnt/ticket-zero + rownorm + gather/dedupe ----------------
__global__ __launch_bounds__(256) void k_prep(
        const float* __restrict__ emb, const int* __restrict__ hist,
        float* __restrict__ rnorm,
        unsigned short* __restrict__ embh, unsigned short* __restrict__ embl,
        float* __restrict__ QgT, double* __restrict__ rqd,
        unsigned short* __restrict__ Qh, unsigned short* __restrict__ Ql,
        unsigned* __restrict__ cnt, unsigned* __restrict__ tick) {
    int bid = blockIdx.x;
    int t = threadIdx.x;
    int lane = t & 63;
    if (bid < 25000) {
        int wid = (bid * 256 + t) >> 6;
        if (wid >= VN) return;
        const float* row = emb + (size_t)wid * DD;
        float2 a = *(const float2*)(row + lane * 2);
        unsigned short h0 = f2bf(a.x), h1 = f2bf(a.y);
        unsigned short l0 = f2bf(a.x - bf2f(h0)), l1 = f2bf(a.y - bf2f(h1));
        ushort2 hv; hv.x = h0; hv.y = h1;
        ushort2 lv; lv.x = l0; lv.y = l1;
        *(ushort2*)(embh + (size_t)wid * DD + lane * 2) = hv;
        *(ushort2*)(embl + (size_t)wid * DD + lane * 2) = lv;
        double ss = (double)a.x * a.x + (double)a.y * a.y;
        ss += __shfl_xor(ss, 1);  ss += __shfl_xor(ss, 2);  ss += __shfl_xor(ss, 4);
        ss += __shfl_xor(ss, 8);  ss += __shfl_xor(ss, 16); ss += __shfl_xor(ss, 32);
        if (lane == 0) {
            double n = sqrt(ss);
            if (n < 1e-12) n = 1e-12;
            rnorm[wid] = (float)(1.0 / n);
        }
    } else {
        if (bid == 25000 && t < 4) {
            if (t == 0) *cnt = 0;
            else tick[t - 1] = 0;
        }
        int gid = (bid - 25000) * 256 + t;
        int wid = gid >> 6;
        if (wid >= BBATCH * HH) return;
        int b = wid >> 6, h = wid & 63;
        int a = hist[wid];
        int hl = hist[(b << 6) + lane];
        unsigned long long m = __ballot((lane < h) && (hl == a));
        bool dup = (m != 0ull);
        const float* row = emb + (size_t)a * DD;
        float2 tv = *(const float2*)(row + lane * 2);
        QgT[((size_t)b * DD + 2 * lane) * 64 + h] = tv.x;
        QgT[((size_t)b * DD + 2 * lane + 1) * 64 + h] = tv.y;
        double ss = (double)tv.x * tv.x + (double)tv.y * tv.y;
        ss += __shfl_xor(ss, 1);  ss += __shfl_xor(ss, 2);  ss += __shfl_xor(ss, 4);
        ss += __shfl_xor(ss, 8);  ss += __shfl_xor(ss, 16); ss += __shfl_xor(ss, 32);
        double n = sqrt(ss);
        if (n < 1e-12) n = 1e-12;
        double r = 1.0 / n;
        float rf = (float)r;
        float sx = tv.x * rf, sy = tv.y * rf;
        unsigned short h0 = f2bf(sx), h1 = f2bf(sy);
        unsigned short l0 = f2bf(sx - bf2f(h0)), l1 = f2bf(sy - bf2f(h1));
        ushort2 hv, lv;
        if (dup) { hv.x = 0; hv.y = 0; lv.x = 0; lv.y = 0; }
        else     { hv.x = h0; hv.y = h1; lv.x = l0; lv.y = l1; }
        *(ushort2*)(Qh + (size_t)wid * DD + lane * 2) = hv;
        *(ushort2*)(Ql + (size_t)wid * DD + lane * 2) = lv;
        if (lane == 0) rqd[wid] = r;
    }
}

// ---------------- K2: MFMA 32x32x16 sims (r11 version, unchanged) ----------------
__global__ __launch_bounds__(512) void k_sims(
        const unsigned short* __restrict__ embh, const unsigned short* __restrict__ embl,
        const unsigned short* __restrict__ Qh, const unsigned short* __restrict__ Ql,
        const float* __restrict__ rnorm, const float* __restrict__ week,
        float* __restrict__ s_arr, float* __restrict__ mw_arr,
        unsigned* __restrict__ cnt, unsigned* __restrict__ flags) {
    int bid = blockIdx.x;
    int logical = (bid & 7) * (NBLK_SIMS / 8) + (bid >> 3);
    int b = logical & 15;
    int vgroup = logical >> 4;
    int t = threadIdx.x;
    int w = t >> 6;
    int lane = t & 63;
    int l31 = lane & 31, l5 = lane >> 5;

    __shared__ unsigned short qlds[2][64 * 128];

    for (int i = 0; i < 2; ++i) {
        int c = t + (i << 9);
        int row = c >> 4, cc = c & 15;
        size_t g = (size_t)(b * 64 + row) * DD + cc * 8;
        unsigned off = (unsigned)((row * 256 + cc * 16)) ^ (unsigned)((row & 7) << 4);
        *(short8*)((char*)&qlds[0][0] + off) = *(const short8*)(Qh + g);
        *(short8*)((char*)&qlds[1][0] + off) = *(const short8*)(Ql + g);
    }
    __syncthreads();

    int vb = vgroup * 512 + w * 64;

    size_t eoff[2];
#pragma unroll
    for (int bt = 0; bt < 2; ++bt) {
        int v = vb + bt * 32 + l31;
        int vc = v < VN ? v : VN - 1;
        eoff[bt] = (size_t)vc * DD + l5 * 8;
    }

    f32x16 acc[2][2];
#pragma unroll
    for (int bt = 0; bt < 2; ++bt)
#pragma unroll
        for (int ht = 0; ht < 2; ++ht)
#pragma unroll
            for (int r = 0; r < 16; ++r) acc[bt][ht][r] = 0.f;

    short8 Bhb[3][2], Blb[3][2];
#pragma unroll
    for (int bt = 0; bt < 2; ++bt) {
        Bhb[0][bt] = *(const short8*)(embh + eoff[bt]);
        Blb[0][bt] = *(const short8*)(embl + eoff[bt]);
    }
#pragma unroll
    for (int bt = 0; bt < 2; ++bt) {
        Bhb[1][bt] = *(const short8*)(embh + eoff[bt] + 16);
        Blb[1][bt] = *(const short8*)(embl + eoff[bt] + 16);
    }

#pragma unroll
    for (int s = 0; s < 8; ++s) {
        const int cur = s % 3;
        if (s < 6) {
            const int pf = (s + 2) % 3;
#pragma unroll
            for (int bt = 0; bt < 2; ++bt) {
                Bhb[pf][bt] = *(const short8*)(embh + eoff[bt] + (s + 2) * 16);
                Blb[pf][bt] = *(const short8*)(embl + eoff[bt] + (s + 2) * 16);
            }
        }
        short8 Ah[2], Al[2];
#pragma unroll
        for (int ht = 0; ht < 2; ++ht) {
            int row = ht * 32 + l31;
            unsigned off = (unsigned)(row * 256 + s * 32 + l5 * 16) ^ (unsigned)((row & 7) << 4);
            Ah[ht] = *(const short8*)((const char*)&qlds[0][0] + off);
            Al[ht] = *(const short8*)((const char*)&qlds[1][0] + off);
        }
#pragma unroll
        for (int bt = 0; bt < 2; ++bt) {
#pragma unroll
            for (int ht = 0; ht < 2; ++ht) {
                acc[bt][ht] = __builtin_amdgcn_mfma_f32_32x32x16_bf16(Ah[ht], Bhb[cur][bt], acc[bt][ht], 0, 0, 0);
                acc[bt][ht] = __builtin_amdgcn_mfma_f32_32x32x16_bf16(Al[ht], Bhb[cur][bt], acc[bt][ht], 0, 0, 0);
                acc[bt][ht] = __builtin_amdgcn_mfma_f32_32x32x16_bf16(Ah[ht], Blb[cur][bt], acc[bt][ht], 0, 0, 0);
            }
        }
    }

#pragma unroll
    for (int bt = 0; bt < 2; ++bt) {
        float m1 = -1e30f, m2 = -1e30f;
        int i1 = 0;
#pragma unroll
        for (int ht = 0; ht < 2; ++ht) {
#pragma unroll
            for (int r = 0; r < 16; ++r) {
                float val = acc[bt][ht][r];
                int h = ht * 32 + (r & 3) + 8 * (r >> 2) + 4 * l5;
                if (val > m1) { m2 = m1; m1 = val; i1 = h; }
                else if (val > m2) m2 = val;
            }
        }
        {
            float o1 = __shfl_xor(m1, 32);
            float o2 = __shfl_xor(m2, 32);
            int   oi = __shfl_xor(i1, 32);
            if (o1 > m1) { m2 = fmaxf(m1, o2); m1 = o1; i1 = oi; }
            else         { m2 = fmaxf(m2, o1); }
        }
        if (lane < 32) {
            int v = vb + bt * 32 + lane;
            if (v < VN) {
                float re = rnorm[v];
                float sv = m1 * re;
                float gap = (m1 - m2) * re;
                if (gap < FLAG_EPS) {
                    unsigned idx = atomicAdd(cnt, 1u);
                    if (idx < FLAG_CAP) flags[idx] = (unsigned)(b * VN + v);
                }
                float sc = fminf(fmaxf(sv, 0.001f), 0.999f);
                float logit = -logf(1.0f / sc - 1.0f);
                int i = b * VN + v;
                s_arr[i] = logit;
                mw_arr[i] = week[b * HH + i1];
            }
        }
    }
}

// ---------------- K3: h-parallel fp64 fixup (r11, unchanged) ----------------
__global__ __launch_bounds__(256) void k_fixup(
        const float* __restrict__ emb, const float* __restrict__ QgT,
        const double* __restrict__ rqd, const float* __restrict__ week,
        const unsigned* __restrict__ cnt, const unsigned* __restrict__ flags,
        float* __restrict__ mw_arr) {
    unsigned n = *cnt;
    if (n > FLAG_CAP) n = FLAG_CAP;
    int lane = threadIdx.x & 63;
    unsigned wid = (blockIdx.x * blockDim.x + threadIdx.x) >> 6;
    unsigned nw = (gridDim.x * blockDim.x) >> 6;
    for (unsigned x = wid; x < n; x += nw) {
        unsigned i = flags[x];
        int b = (int)(i / VN);
        int v = (int)(i - (unsigned)b * VN);
        const float* e = emb + (size_t)v * DD;
        const float* qT = QgT + (size_t)b * DD * 64;
        double s0 = 0, s1 = 0, s2 = 0, s3 = 0;
        for (int k = 0; k < DD; k += 4) {
            float4 ev = *(const float4*)(e + k);
            s0 += (double)ev.x * (double)qT[(k    ) * 64 + lane];
            s1 += (double)ev.y * (double)qT[(k + 1) * 64 + lane];
            s2 += (double)ev.z * (double)qT[(k + 2) * 64 + lane];
            s3 += (double)ev.w * (double)qT[(k + 3) * 64 + lane];
        }
        double sim = ((s0 + s1) + (s2 + s3)) * rqd[b * 64 + lane];
        int bh = lane;
#pragma unroll
        for (int mask = 1; mask <= 32; mask <<= 1) {
            double o = __shfl_xor(sim, mask);
            int oh = __shfl_xor(bh, mask);
            if (o > sim || (o == sim && oh < bh)) { sim = o; bh = oh; }
        }
        if (lane == 0) mw_arr[i] = week[b * HH + bh];
    }
}

// ---- last-block finalize helper: reduces part[nb][2C] -> scsh[2C] (deterministic order) ----
template <int C>
__device__ void winner_finalize(const float* part, int nb,
                                const float* g, const float* be,
                                float* scsh, double* redd) {
    constexpr int S = 2 * C;
    constexpr int G = 256 / S;
    int t = threadIdx.x;
    int st = t % S, gr = t / S;
    double acc = 0;
    for (int i = gr; i < nb; i += G) acc += (double)part[(size_t)i * S + st];
    redd[t] = acc;
    __syncthreads();
    if (t < S) {
        double tot = redd[t];
        for (int g2 = 1; g2 < G; ++g2) tot += redd[t + g2 * S];
        redd[t] = tot;
    }
    __syncthreads();
    if (t < C) {
        double mean = redd[t] / (double)NEL;
        double var = redd[C + t] / (double)NEL - mean * mean;
        float r = (float)(1.0 / sqrt(var + 1e-5));
        float sc = g[t] * r;
        float sh = be[t] - (float)mean * sc;
        scsh[t] = sc;
        scsh[C + t] = sh;
    }
}

// ---------------- K4: stat1 + last-block fin1 ----------------
__global__ __launch_bounds__(256) void k_stat1(
        const float* __restrict__ s_arr, const float* __restrict__ mw_arr,
        const float* __restrict__ lik,
        const float* __restrict__ w1g, const float* __restrict__ b1g,
        const float* __restrict__ g1, const float* __restrict__ be1,
        float* part1, float* scsh1, unsigned* tick) {
    __shared__ __align__(16) float w1s[8][4];
    __shared__ float bb1[8];
    __shared__ float lred[4][16];
    __shared__ double redd[256];
    __shared__ unsigned oldt;
    int t = threadIdx.x;
    if (t < 32) { int o = t >> 2, c = t & 3; w1s[o][c] = (c < 3) ? w1g[o * 3 + c] : 0.f; }
    if (t < 8) bb1[t] = b1g[t];
    __syncthreads();

    float ps[16];
#pragma unroll
    for (int s = 0; s < 16; ++s) ps[s] = 0.f;
    int base = blockIdx.x * 1024 + t;
#pragma unroll
    for (int e = 0; e < 4; ++e) {
        int i = base + (e << 8);
        if (i < NEL) {
            int bq = i / VN;
            int v = i - bq * VN;
            float f0 = s_arr[i], f1 = mw_arr[i], f2 = lik[v];
#pragma unroll
            for (int o = 0; o < 8; ++o) {
                float4 wr = *(const float4*)&w1s[o][0];
                float z = bb1[o];
                z = fmaf(wr.x, f0, z);
                z = fmaf(wr.y, f1, z);
                z = fmaf(wr.z, f2, z);
                z = leaky1(z);
                ps[o] += z;
                ps[8 + o] += z * z;
            }
        }
    }
    int lane = t & 63, w = t >> 6;
#pragma unroll
    for (int s = 0; s < 16; ++s) {
        float v2 = ps[s];
        v2 += __shfl_xor(v2, 1);  v2 += __shfl_xor(v2, 2);  v2 += __shfl_xor(v2, 4);
        v2 += __shfl_xor(v2, 8);  v2 += __shfl_xor(v2, 16); v2 += __shfl_xor(v2, 32);
        if (lane == 0) lred[w][s] = v2;
    }
    __syncthreads();
    if (t < 16) part1[blockIdx.x * 16 + t] = lred[0][t] + lred[1][t] + lred[2][t] + lred[3][t];

    // last block computes fin1
    __threadfence();
    if (t == 0) oldt = atomicAdd(tick, 1u);
    __syncthreads();
    if (oldt == (unsigned)(gridDim.x - 1)) {
        __threadfence();
        winner_finalize<8>(part1, NB_STAT, g1, be1, scsh1, redd);
    }
}

// ---------------- K5: stat2 (reads scsh1) + last-block fin2 ----------------
__global__ __launch_bounds__(256) void k_stat2(
        const float* __restrict__ s_arr, const float* __restrict__ mw_arr,
        const float* __restrict__ lik,
        const float* __restrict__ w1g, const float* __restrict__ b1g,
        const float* __restrict__ scsh1,
        const float* __restrict__ g2, const float* __restrict__ be2,
        const float* __restrict__ w2g, const float* __restrict__ b2g,
        float* part2, float* scsh2, unsigned* tick) {
    int t = threadIdx.x;
    __shared__ double redd[256];
    __shared__ unsigned oldt;
    int c = t & 15, g = t >> 4;
    float w1r[8][3], bb1[8], sc1[8], sh1[8];
#pragma unroll
    for (int o = 0; o < 8; ++o) {
        w1r[o][0] = w1g[o * 3];
        w1r[o][1] = w1g[o * 3 + 1];
        w1r[o][2] = w1g[o * 3 + 2];
        bb1[o] = b1g[o];
        sc1[o] = scsh1[o];
        sh1[o] = scsh1[8 + o];
    }
    float4 waL = *(const float4*)(w2g + c * 8);
    float4 wbL = *(const float4*)(w2g + c * 8 + 4);
    float4 waH = *(const float4*)(w2g + (c + 16) * 8);
    float4 wbH = *(const float4*)(w2g + (c + 16) * 8 + 4);
    float zbL = b2g[c], zbH = b2g[c + 16];

    float ps0L = 0.f, ps1L = 0.f, ps0H = 0.f, ps1H = 0.f;
    int base = blockIdx.x * 1024 + g;
    int vcur = base % VN;
#pragma unroll 4
    for (int it = 0; it < 64; ++it) {
        int i = base + it * 16;
        if (i < NEL) {
            float f0 = s_arr[i], f1 = mw_arr[i], f2 = lik[vcur];
            float y1[8];
#pragma unroll
            for (int o = 0; o < 8; ++o) {
                float z = bb1[o];
                z = fmaf(w1r[o][0], f0, z);
                z = fmaf(w1r[o][1], f1, z);
                z = fmaf(w1r[o][2], f2, z);
                z = leaky1(z);
                y1[o] = fmaf(z, sc1[o], sh1[o]);
            }
            float zL = zbL;
            zL = fmaf(waL.x, y1[0], zL); zL = fmaf(waL.y, y1[1], zL);
            zL = fmaf(waL.z, y1[2], zL); zL = fmaf(waL.w, y1[3], zL);
            zL = fmaf(wbL.x, y1[4], zL); zL = fmaf(wbL.y, y1[5], zL);
            zL = fmaf(wbL.z, y1[6], zL); zL = fmaf(wbL.w, y1[7], zL);
            zL = leaky1(zL);
            ps0L += zL; ps1L += zL * zL;
            float zH = zbH;
            zH = fmaf(waH.x, y1[0], zH); zH = fmaf(waH.y, y1[1], zH);
            zH = fmaf(waH.z, y1[2], zH); zH = fmaf(waH.w, y1[3], zH);
            zH = fmaf(wbH.x, y1[4], zH); zH = fmaf(wbH.y, y1[5], zH);
            zH = fmaf(wbH.z, y1[6], zH); zH = fmaf(wbH.w, y1[7], zH);
            zH = leaky1(zH);
            ps0H += zH; ps1H += zH * zH;
        }
        vcur += 16;
        if (vcur >= VN) vcur -= VN;
    }
    __shared__ float red[4][256];
    red[0][t] = ps0L;
    red[1][t] = ps0H;
    red[2][t] = ps1L;
    red[3][t] = ps1H;
    __syncthreads();
    if (t < 64) {
        int which = t >> 5;
        int ch = t & 31;
        int arr = which * 2 + (ch >> 4);
        int cl = ch & 15;
        float s = 0.f;
#pragma unroll
        for (int gg = 0; gg < 16; ++gg) s += red[arr][gg * 16 + cl];
        part2[blockIdx.x * 64 + t] = s;
    }

    __threadfence();
    if (t == 0) oldt = atomicAdd(tick, 1u);
    __syncthreads();
    if (oldt == (unsigned)(gridDim.x - 1)) {
        __threadfence();
        winner_finalize<32>(part2, NB_STAT, g2, be2, scsh2, redd);
    }
}

// ---------------- K6: stat3 (reads scsh1, scsh2) + last-block fin3 ----------------
__global__ __launch_bounds__(256) void k_stat3(
        const float* __restrict__ s_arr, const float* __restrict__ mw_arr,
        const float* __restrict__ lik,
        const float* __restrict__ w1g, const float* __restrict__ b1g,
        const float* __restrict__ scsh1,
        const float* __restrict__ scsh2,
        const float* __restrict__ g3, const float* __restrict__ be3,
        const float* __restrict__ w2g, const float* __restrict__ b2g,
        const float* __restrict__ w3g, const float* __restrict__ b3g,
        float* part3, float* scsh3, unsigned* tick) {
    __shared__ __align__(16) float w1s[8][4];
    __shared__ __align__(16) float w2s[32][8];
    __shared__ __align__(16) float w3t[32][8];
    __shared__ float bb1[8], sc1[8], sh1[8];
    __shared__ float bb2[32], sc2[32], sh2[32];
    __shared__ float bb3[8];
    __shared__ float lred[4][16];
    __shared__ double redd[256];
    __shared__ unsigned oldt;
    int t = threadIdx.x;
    if (t < 32) { int o = t >> 2, c = t & 3; w1s[o][c] = (c < 3) ? w1g[o * 3 + c] : 0.f; }
    if (t < 8) { bb1[t] = b1g[t]; sc1[t] = scsh1[t]; sh1[t] = scsh1[8 + t]; bb3[t] = b3g[t]; }
    if (t < 256) { w2s[t >> 3][t & 7] = w2g[t]; w3t[t & 31][t >> 5] = w3g[t]; }
    if (t < 32) { bb2[t] = b2g[t]; sc2[t] = scsh2[t]; sh2[t] = scsh2[32 + t]; }
    __syncthreads();

    int base = blockIdx.x * 1024 + t;
    int vb0 = base % VN;
    bool ok[4];
    float y1[8][4];
#pragma unroll
    for (int e = 0; e < 4; ++e) {
        int i = base + (e << 8);
        ok[e] = (i < NEL);
        float f0 = 0.f, f1 = 0.f, f2 = 0.f;
        if (ok[e]) {
            int v = vb0 + (e << 8);
            if (v >= VN) v -= VN;
            f0 = s_arr[i]; f1 = mw_arr[i]; f2 = lik[v];
        }
#pragma unroll
        for (int o = 0; o < 8; ++o) {
            float4 wr = *(const float4*)&w1s[o][0];
            float z = bb1[o];
            z = fmaf(wr.x, f0, z); z = fmaf(wr.y, f1, z); z = fmaf(wr.z, f2, z);
            z = leaky1(z);
            y1[o][e] = fmaf(z, sc1[o], sh1[o]);
        }
    }
    float z3[8][4];
#pragma unroll
    for (int o3 = 0; o3 < 8; ++o3) {
        float bv = bb3[o3];
#pragma unroll
        for (int e = 0; e < 4; ++e) z3[o3][e] = bv;
    }
#pragma unroll 4
    for (int o = 0; o < 32; ++o) {
        float4 wa = *(const float4*)&w2s[o][0];
        float4 wb = *(const float4*)&w2s[o][4];
        float4 ua = *(const float4*)&w3t[o][0];
        float4 ub = *(const float4*)&w3t[o][4];
        float zb = bb2[o], sc = sc2[o], sh = sh2[o];
#pragma unroll
        for (int e = 0; e < 4; ++e) {
            float z = zb;
            z = fmaf(wa.x, y1[0][e], z); z = fmaf(wa.y, y1[1][e], z);
            z = fmaf(wa.z, y1[2][e], z); z = fmaf(wa.w, y1[3][e], z);
            z = fmaf(wb.x, y1[4][e], z); z = fmaf(wb.y, y1[5][e], z);
            z = fmaf(wb.z, y1[6][e], z); z = fmaf(wb.w, y1[7][e], z);
            z = leaky1(z);
            float y2 = fmaf(z, sc, sh);
            z3[0][e] = fmaf(ua.x, y2, z3[0][e]);
            z3[1][e] = fmaf(ua.y, y2, z3[1][e]);
            z3[2][e] = fmaf(ua.z, y2, z3[2][e]);
            z3[3][e] = fmaf(ua.w, y2, z3[3][e]);
            z3[4][e] = fmaf(ub.x, y2, z3[4][e]);
            z3[5][e] = fmaf(ub.y, y2, z3[5][e]);
            z3[6][e] = fmaf(ub.z, y2, z3[6][e]);
            z3[7][e] = fmaf(ub.w, y2, z3[7][e]);
        }
    }
    float ps[16];
#pragma unroll
    for (int s = 0; s < 16; ++s) ps[s] = 0.f;
#pragma unroll
    for (int e = 0; e < 4; ++e) {
        if (!ok[e]) continue;
#pragma unroll
        for (int o3 = 0; o3 < 8; ++o3) {
            float z = leaky1(z3[o3][e]);
            ps[o3] += z;
            ps[8 + o3] += z * z;
        }
    }
    int lane = t & 63, w = t >> 6;
#pragma unroll
    for (int s = 0; s < 16; ++s) {
        float v2 = ps[s];
        v2 += __shfl_xor(v2, 1);  v2 += __shfl_xor(v2, 2);  v2 += __shfl_xor(v2, 4);
        v2 += __shfl_xor(v2, 8);  v2 += __shfl_xor(v2, 16); v2 += __shfl_xor(v2, 32);
        if (lane == 0) lred[w][s] = v2;
    }
    __syncthreads();
    if (t < 16) part3[blockIdx.x * 16 + t] = lred[0][t] + lred[1][t] + lred[2][t] + lred[3][t];

    __threadfence();
    if (t == 0) oldt = atomicAdd(tick, 1u);
    __syncthreads();
    if (oldt == (unsigned)(gridDim.x - 1)) {
        __threadfence();
        winner_finalize<8>(part3, NB_STAT, g3, be3, scsh3, redd);
    }
}

// ---------------- K7: output (reads scsh1/2/3) ----------------
__global__ __launch_bounds__(256) void k_out(
        const float* __restrict__ s_arr, const float* __restrict__ mw_arr,
        const float* __restrict__ lik,
        const float* __restrict__ w1g, const float* __restrict__ b1g,
        const float* __restrict__ scsh1,
        const float* __restrict__ w2g, const float* __restrict__ b2g,
        const float* __restrict__ scsh2,
        const float* __restrict__ w3g, const float* __restrict__ b3g,
        const float* __restrict__ scsh3,
        const float* __restrict__ w4g, const float* __restrict__ b4g,
        float* __restrict__ outp) {
    __shared__ __align__(16) float w1s[8][4];
    __shared__ __align__(16) float w2s[32][8];
    __shared__ __align__(16) float w3t[32][8];
    __shared__ float bb1[8], sc1[8], sh1[8];
    __shared__ float bb2[32], sc2[32], sh2[32];
    __shared__ float bb3[8], sc3[8], sh3[8], w4s[8];
    __shared__ float bb4s;
    int t = threadIdx.x;
    if (t < 32) { int o = t >> 2, c = t & 3; w1s[o][c] = (c < 3) ? w1g[o * 3 + c] : 0.f; }
    if (t < 8) {
        bb1[t] = b1g[t]; sc1[t] = scsh1[t]; sh1[t] = scsh1[8 + t];
        bb3[t] = b3g[t]; sc3[t] = scsh3[t]; sh3[t] = scsh3[8 + t];
        w4s[t] = w4g[t];
    }
    if (t < 256) { w2s[t >> 3][t & 7] = w2g[t]; w3t[t & 31][t >> 5] = w3g[t]; }
    if (t < 32) { bb2[t] = b2g[t]; sc2[t] = scsh2[t]; sh2[t] = scsh2[32 + t]; }
    if (t == 0) bb4s = b4g[0];
    __syncthreads();

    int base = blockIdx.x * 1024 + t;
    int vb0 = base % VN;
    bool ok[4];
    float y1[8][4];
#pragma unroll
    for (int e = 0; e < 4; ++e) {
        int i = base + (e << 8);
        ok[e] = (i < NEL);
        float f0 = 0.f, f1 = 0.f, f2 = 0.f;
        if (ok[e]) {
            int v = vb0 + (e << 8);
            if (v >= VN) v -= VN;
            f0 = s_arr[i]; f1 = mw_arr[i]; f2 = lik[v];
        }
#pragma unroll
        for (int o = 0; o < 8; ++o) {
            float4 wr = *(const float4*)&w1s[o][0];
            float z = bb1[o];
            z = fmaf(wr.x, f0, z); z = fmaf(wr.y, f1, z); z = fmaf(wr.z, f2, z);
            z = leaky1(z);
            y1[o][e] = fmaf(z, sc1[o], sh1[o]);
        }
    }
    float z3[8][4];
#pragma unroll
    for (int o3 = 0; o3 < 8; ++o3) {
        float bv = bb3[o3];
#pragma unroll
        for (int e = 0; e < 4; ++e) z3[o3][e] = bv;
    }
#pragma unroll 4
    for (int o = 0; o < 32; ++o) {
        float4 wa = *(const float4*)&w2s[o][0];
        float4 wb = *(const float4*)&w2s[o][4];
        float4 ua = *(const float4*)&w3t[o][0];
        float4 ub = *(const float4*)&w3t[o][4];
        float zb = bb2[o], sc = sc2[o], sh = sh2[o];
#pragma unroll
        for (int e = 0; e < 4; ++e) {
            float z = zb;
            z = fmaf(wa.x, y1[0][e], z); z = fmaf(wa.y, y1[1][e], z);
            z = fmaf(wa.z, y1[2][e], z); z = fmaf(wa.w, y1[3][e], z);
            z = fmaf(wb.x, y1[4][e], z); z = fmaf(wb.y, y1[5][e], z);
            z = fmaf(wb.z, y1[6][e], z); z = fmaf(wb.w, y1[7][e], z);
            z = leaky1(z);
            float y2 = fmaf(z, sc, sh);
            z3[0][e] = fmaf(ua.x, y2, z3[0][e]);
            z3[1][e] = fmaf(ua.y, y2, z3[1][e]);
            z3[2][e] = fmaf(ua.z, y2, z3[2][e]);
            z3[3][e] = fmaf(ua.w, y2, z3[3][e]);
            z3[4][e] = fmaf(ub.x, y2, z3[4][e]);
            z3[5][e] = fmaf(ub.y, y2, z3[5][e]);
            z3[6][e] = fmaf(ub.z, y2, z3[6][e]);
            z3[7][e] = fmaf(ub.w, y2, z3[7][e]);
        }
    }
#pragma unroll
    for (int e = 0; e < 4; ++e) {
        if (!ok[e]) continue;
        float oacc = bb4s;
#pragma unroll
        for (int o3 = 0; o3 < 8; ++o3) {
            float z = leaky1(z3[o3][e]);
            float y3 = fmaf(z, sc3[o3], sh3[o3]);
            oacc = fmaf(w4s[o3], y3, oacc);
        }
        outp[base + (e << 8)] = oacc;
    }
}

extern "C" void kernel_launch(void* const* d_in, const int* in_sizes, int n_in,
                              void* d_out, int out_size, void* d_ws, size_t ws_size,
                              hipStream_t stream) {
    const int*   hist = (const int*)d_in[0];
    const float* week = (const float*)d_in[1];
    const float* emb  = (const float*)d_in[2];
    const float* lik  = (const float*)d_in[3];
    const float* w1 = (const float*)d_in[4];
    const float* b1 = (const float*)d_in[5];
    const float* g1 = (const float*)d_in[6];
    const float* be1 = (const float*)d_in[7];
    const float* w2 = (const float*)d_in[8];
    const float* b2 = (const float*)d_in[9];
    const float* g2 = (const float*)d_in[10];
    const float* be2 = (const float*)d_in[11];
    const float* w3 = (const float*)d_in[12];
    const float* b3 = (const float*)d_in[13];
    const float* g3 = (const float*)d_in[14];
    const float* be3 = (const float*)d_in[15];
    const float* w4 = (const float*)d_in[16];
    const float* b4 = (const float*)d_in[17];
    float* outp = (float*)d_out;
    char* ws = (char*)d_ws;

    unsigned* cnt   = (unsigned*)(ws + OFF_CNT);
    unsigned* tick  = (unsigned*)(ws + OFF_TICK);
    unsigned* flags = (unsigned*)(ws + OFF_FLAG);
    float* rnorm = (float*)(ws + OFF_RNORM);
    double* rqd  = (double*)(ws + OFF_RQD);
    float* QgT   = (float*)(ws + OFF_QG);
    float* s_arr = (float*)(ws + OFF_S);
    float* mw    = (float*)(ws + OFF_MW);
    float* part1 = (float*)(ws + OFF_PART1);
    float* part2 = (float*)(ws + OFF_PART2);
    float* part3 = (float*)(ws + OFF_PART3);
    float* scsh1 = (float*)(ws + OFF_SCSH1);
    float* scsh2 = (float*)(ws + OFF_SCSH2);
    float* scsh3 = (float*)(ws + OFF_SCSH3);
    unsigned short* embh = (unsigned short*)(ws + OFF_EMBH);
    unsigned short* embl = (unsigned short*)(ws + OFF_EMBL);
    unsigned short* Qhp  = (unsigned short*)(ws + OFF_QH);
    unsigned short* Qlp  = (unsigned short*)(ws + OFF_QL);

    k_prep<<<25256, 256, 0, stream>>>(emb, hist, rnorm, embh, embl, QgT, rqd, Qhp, Qlp, cnt, tick);
    k_sims<<<NBLK_SIMS, 512, 0, stream>>>(embh, embl, Qhp, Qlp, rnorm, week, s_arr, mw, cnt, flags);
    k_fixup<<<1024, 256, 0, stream>>>(emb, QgT, rqd, week, cnt, flags, mw);
    k_stat1<<<NB_STAT, 256, 0, stream>>>(s_arr, mw, lik, w1, b1, g1, be1, part1, scsh1, tick);
    k_stat2<<<NB_STAT, 256, 0, stream>>>(s_arr, mw, lik, w1, b1, scsh1, g2, be2, w2, b2, part2, scsh2, tick + 1);
    k_stat3<<<NB_STAT, 256, 0, stream>>>(s_arr, mw, lik, w1, b1, scsh1, scsh2, g3, be3, w2, b2, w3, b3, part3, scsh3, tick + 2);
    k_out<<<NB_STAT, 256, 0, stream>>>(s_arr, mw, lik, w1, b1, scsh1, w2, b2, scsh2, w3, b3, scsh3, w4, b4, outp);
    (void)in_sizes; (void)n_in; (void)out_size; (void)ws_size;
}

// Round 17
// 310.065 us; speedup vs baseline: 2.1513x; 2.1513x over previous
//
#include <hip/hip_runtime.h>
#include <math.h>

#define VN 100000
#define DD 128
#define BBATCH 16
#define HH 64
#define NEL (BBATCH*VN)   // 1,600,000
#define NB_STAT 1563      // chunks of 1024
#define NB2 512           // stat2/stat3 grid (chunk-stride)
#define NVGRP 196
#define NBLK_SIMS (16*NVGRP)  // 3136, divisible by 8

#define FLAG_CAP 262144u
#define FLAG_EPS 4e-5f

// ---- workspace layout (bytes) ----
#define OFF_CNT    0
#define OFF_FLAG   1024
#define OFF_RNORM  (OFF_FLAG + FLAG_CAP*4)
#define OFF_RQD    (OFF_RNORM + VN*4)
#define OFF_QG     (OFF_RQD + 1024*8)          // QgT (fp32, b x k x h = 512KB)
#define OFF_S      (OFF_QG + 1024*DD*4)
#define OFF_MW     (OFF_S + NEL*4)
#define OFF_PART1  (OFF_MW + NEL*4)            // 1563*16*4
#define OFF_PART2  (OFF_PART1 + NB_STAT*16*4)  // 512*64*4
#define OFF_PART3  (OFF_PART2 + NB2*64*4)      // 512*16*4
#define OFF_SCSH1  (OFF_PART3 + NB2*16*4)
#define OFF_SCSH2  (OFF_SCSH1 + 256)
#define OFF_EMBH   ((size_t)(OFF_SCSH2 + 256))
#define OFF_EMBL   (OFF_EMBH + (size_t)VN*DD*2)
#define OFF_QH     (OFF_EMBL + (size_t)VN*DD*2)
#define OFF_QL     (OFF_QH + (size_t)1024*DD*2)

typedef __attribute__((ext_vector_type(8))) short short8;
typedef __attribute__((ext_vector_type(16))) float f32x16;

__device__ __forceinline__ float leaky1(float x) { return x >= 0.f ? x : 0.01f * x; }

__device__ __forceinline__ unsigned short f2bf(float f) {
    unsigned u = __float_as_uint(f);
    u += 0x7fffu + ((u >> 16) & 1u);
    return (unsigned short)(u >> 16);
}
__device__ __forceinline__ float bf2f(unsigned short s) {
    return __uint_as_float(((unsigned)s) << 16);
}

// ---------------- K1: prep = cnt-zero + rownorm + gather/dedupe (r13, proven) ----------------
__global__ __launch_bounds__(256) void k_prep(
        const float* __restrict__ emb, const int* __restrict__ hist,
        float* __restrict__ rnorm,
        unsigned short* __restrict__ embh, unsigned short* __restrict__ embl,
        float* __restrict__ QgT, double* __restrict__ rqd,
        unsigned short* __restrict__ Qh, unsigned short* __restrict__ Ql,
        unsigned* __restrict__ cnt) {
    int bid = blockIdx.x;
    int t = threadIdx.x;
    int lane = t & 63;
    if (bid < 25000) {
        int wid = (bid * 256 + t) >> 6;
        if (wid >= VN) return;
        const float* row = emb + (size_t)wid * DD;
        float2 a = *(const float2*)(row + lane * 2);
        unsigned short h0 = f2bf(a.x), h1 = f2bf(a.y);
        unsigned short l0 = f2bf(a.x - bf2f(h0)), l1 = f2bf(a.y - bf2f(h1));
        ushort2 hv; hv.x = h0; hv.y = h1;
        ushort2 lv; lv.x = l0; lv.y = l1;
        *(ushort2*)(embh + (size_t)wid * DD + lane * 2) = hv;
        *(ushort2*)(embl + (size_t)wid * DD + lane * 2) = lv;
        double ss = (double)a.x * a.x + (double)a.y * a.y;
        ss += __shfl_xor(ss, 1);  ss += __shfl_xor(ss, 2);  ss += __shfl_xor(ss, 4);
        ss += __shfl_xor(ss, 8);  ss += __shfl_xor(ss, 16); ss += __shfl_xor(ss, 32);
        if (lane == 0) {
            double n = sqrt(ss);
            if (n < 1e-12) n = 1e-12;
            rnorm[wid] = (float)(1.0 / n);
        }
    } else {
        if (bid == 25000 && t == 0) *cnt = 0;
        int gid = (bid - 25000) * 256 + t;
        int wid = gid >> 6;
        if (wid >= BBATCH * HH) return;
        int b = wid >> 6, h = wid & 63;
        int a = hist[wid];
        int hl = hist[(b << 6) + lane];
        unsigned long long m = __ballot((lane < h) && (hl == a));
        bool dup = (m != 0ull);
        const float* row = emb + (size_t)a * DD;
        float2 tv = *(const float2*)(row + lane * 2);
        QgT[((size_t)b * DD + 2 * lane) * 64 + h] = tv.x;
        QgT[((size_t)b * DD + 2 * lane + 1) * 64 + h] = tv.y;
        double ss = (double)tv.x * tv.x + (double)tv.y * tv.y;
        ss += __shfl_xor(ss, 1);  ss += __shfl_xor(ss, 2);  ss += __shfl_xor(ss, 4);
        ss += __shfl_xor(ss, 8);  ss += __shfl_xor(ss, 16); ss += __shfl_xor(ss, 32);
        double n = sqrt(ss);
        if (n < 1e-12) n = 1e-12;
        double r = 1.0 / n;
        float rf = (float)r;
        float sx = tv.x * rf, sy = tv.y * rf;
        unsigned short h0 = f2bf(sx), h1 = f2bf(sy);
        unsigned short l0 = f2bf(sx - bf2f(h0)), l1 = f2bf(sy - bf2f(h1));
        ushort2 hv, lv;
        if (dup) { hv.x = 0; hv.y = 0; lv.x = 0; lv.y = 0; }
        else     { hv.x = h0; hv.y = h1; lv.x = l0; lv.y = l1; }
        *(ushort2*)(Qh + (size_t)wid * DD + lane * 2) = hv;
        *(ushort2*)(Ql + (size_t)wid * DD + lane * 2) = lv;
        if (lane == 0) rqd[wid] = r;
    }
}

// ---------------- K2: MFMA 32x32x16 sims (r11 version, unchanged) ----------------
__global__ __launch_bounds__(512) void k_sims(
        const unsigned short* __restrict__ embh, const unsigned short* __restrict__ embl,
        const unsigned short* __restrict__ Qh, const unsigned short* __restrict__ Ql,
        const float* __restrict__ rnorm, const float* __restrict__ week,
        float* __restrict__ s_arr, float* __restrict__ mw_arr,
        unsigned* __restrict__ cnt, unsigned* __restrict__ flags) {
    int bid = blockIdx.x;
    int logical = (bid & 7) * (NBLK_SIMS / 8) + (bid >> 3);
    int b = logical & 15;
    int vgroup = logical >> 4;
    int t = threadIdx.x;
    int w = t >> 6;
    int lane = t & 63;
    int l31 = lane & 31, l5 = lane >> 5;

    __shared__ unsigned short qlds[2][64 * 128];

    for (int i = 0; i < 2; ++i) {
        int c = t + (i << 9);
        int row = c >> 4, cc = c & 15;
        size_t g = (size_t)(b * 64 + row) * DD + cc * 8;
        unsigned off = (unsigned)((row * 256 + cc * 16)) ^ (unsigned)((row & 7) << 4);
        *(short8*)((char*)&qlds[0][0] + off) = *(const short8*)(Qh + g);
        *(short8*)((char*)&qlds[1][0] + off) = *(const short8*)(Ql + g);
    }
    __syncthreads();

    int vb = vgroup * 512 + w * 64;

    size_t eoff[2];
#pragma unroll
    for (int bt = 0; bt < 2; ++bt) {
        int v = vb + bt * 32 + l31;
        int vc = v < VN ? v : VN - 1;
        eoff[bt] = (size_t)vc * DD + l5 * 8;
    }

    f32x16 acc[2][2];
#pragma unroll
    for (int bt = 0; bt < 2; ++bt)
#pragma unroll
        for (int ht = 0; ht < 2; ++ht)
#pragma unroll
            for (int r = 0; r < 16; ++r) acc[bt][ht][r] = 0.f;

    short8 Bhb[3][2], Blb[3][2];
#pragma unroll
    for (int bt = 0; bt < 2; ++bt) {
        Bhb[0][bt] = *(const short8*)(embh + eoff[bt]);
        Blb[0][bt] = *(const short8*)(embl + eoff[bt]);
    }
#pragma unroll
    for (int bt = 0; bt < 2; ++bt) {
        Bhb[1][bt] = *(const short8*)(embh + eoff[bt] + 16);
        Blb[1][bt] = *(const short8*)(embl + eoff[bt] + 16);
    }

#pragma unroll
    for (int s = 0; s < 8; ++s) {
        const int cur = s % 3;
        if (s < 6) {
            const int pf = (s + 2) % 3;
#pragma unroll
            for (int bt = 0; bt < 2; ++bt) {
                Bhb[pf][bt] = *(const short8*)(embh + eoff[bt] + (s + 2) * 16);
                Blb[pf][bt] = *(const short8*)(embl + eoff[bt] + (s + 2) * 16);
            }
        }
        short8 Ah[2], Al[2];
#pragma unroll
        for (int ht = 0; ht < 2; ++ht) {
            int row = ht * 32 + l31;
            unsigned off = (unsigned)(row * 256 + s * 32 + l5 * 16) ^ (unsigned)((row & 7) << 4);
            Ah[ht] = *(const short8*)((const char*)&qlds[0][0] + off);
            Al[ht] = *(const short8*)((const char*)&qlds[1][0] + off);
        }
#pragma unroll
        for (int bt = 0; bt < 2; ++bt) {
#pragma unroll
            for (int ht = 0; ht < 2; ++ht) {
                acc[bt][ht] = __builtin_amdgcn_mfma_f32_32x32x16_bf16(Ah[ht], Bhb[cur][bt], acc[bt][ht], 0, 0, 0);
                acc[bt][ht] = __builtin_amdgcn_mfma_f32_32x32x16_bf16(Al[ht], Bhb[cur][bt], acc[bt][ht], 0, 0, 0);
                acc[bt][ht] = __builtin_amdgcn_mfma_f32_32x32x16_bf16(Ah[ht], Blb[cur][bt], acc[bt][ht], 0, 0, 0);
            }
        }
    }

#pragma unroll
    for (int bt = 0; bt < 2; ++bt) {
        float m1 = -1e30f, m2 = -1e30f;
        int i1 = 0;
#pragma unroll
        for (int ht = 0; ht < 2; ++ht) {
#pragma unroll
            for (int r = 0; r < 16; ++r) {
                float val = acc[bt][ht][r];
                int h = ht * 32 + (r & 3) + 8 * (r >> 2) + 4 * l5;
                if (val > m1) { m2 = m1; m1 = val; i1 = h; }
                else if (val > m2) m2 = val;
            }
        }
        {
            float o1 = __shfl_xor(m1, 32);
            float o2 = __shfl_xor(m2, 32);
            int   oi = __shfl_xor(i1, 32);
            if (o1 > m1) { m2 = fmaxf(m1, o2); m1 = o1; i1 = oi; }
            else         { m2 = fmaxf(m2, o1); }
        }
        if (lane < 32) {
            int v = vb + bt * 32 + lane;
            if (v < VN) {
                float re = rnorm[v];
                float sv = m1 * re;
                float gap = (m1 - m2) * re;
                if (gap < FLAG_EPS) {
                    unsigned idx = atomicAdd(cnt, 1u);
                    if (idx < FLAG_CAP) flags[idx] = (unsigned)(b * VN + v);
                }
                float sc = fminf(fmaxf(sv, 0.001f), 0.999f);
                float logit = -logf(1.0f / sc - 1.0f);
                int i = b * VN + v;
                s_arr[i] = logit;
                mw_arr[i] = week[b * HH + i1];
            }
        }
    }
}

// ---------------- K3: h-parallel fp64 fixup (r11, unchanged) ----------------
__global__ __launch_bounds__(256) void k_fixup(
        const float* __restrict__ emb, const float* __restrict__ QgT,
        const double* __restrict__ rqd, const float* __restrict__ week,
        const unsigned* __restrict__ cnt, const unsigned* __restrict__ flags,
        float* __restrict__ mw_arr) {
    unsigned n = *cnt;
    if (n > FLAG_CAP) n = FLAG_CAP;
    int lane = threadIdx.x & 63;
    unsigned wid = (blockIdx.x * blockDim.x + threadIdx.x) >> 6;
    unsigned nw = (gridDim.x * blockDim.x) >> 6;
    for (unsigned x = wid; x < n; x += nw) {
        unsigned i = flags[x];
        int b = (int)(i / VN);
        int v = (int)(i - (unsigned)b * VN);
        const float* e = emb + (size_t)v * DD;
        const float* qT = QgT + (size_t)b * DD * 64;
        double s0 = 0, s1 = 0, s2 = 0, s3 = 0;
        for (int k = 0; k < DD; k += 4) {
            float4 ev = *(const float4*)(e + k);
            s0 += (double)ev.x * (double)qT[(k    ) * 64 + lane];
            s1 += (double)ev.y * (double)qT[(k + 1) * 64 + lane];
            s2 += (double)ev.z * (double)qT[(k + 2) * 64 + lane];
            s3 += (double)ev.w * (double)qT[(k + 3) * 64 + lane];
        }
        double sim = ((s0 + s1) + (s2 + s3)) * rqd[b * 64 + lane];
        int bh = lane;
#pragma unroll
        for (int mask = 1; mask <= 32; mask <<= 1) {
            double o = __shfl_xor(sim, mask);
            int oh = __shfl_xor(bh, mask);
            if (o > sim || (o == sim && oh < bh)) { sim = o; bh = oh; }
        }
        if (lane == 0) mw_arr[i] = week[b * HH + bh];
    }
}

// ---------------- K4: layer-1 stats (r11, unchanged) ----------------
__global__ __launch_bounds__(256) void k_stat1(
        const float* __restrict__ s_arr, const float* __restrict__ mw_arr,
        const float* __restrict__ lik,
        const float* __restrict__ w1g, const float* __restrict__ b1g,
        float* __restrict__ part1) {
    __shared__ __align__(16) float w1s[8][4];
    __shared__ float bb1[8];
    __shared__ float lred[4][16];
    int t = threadIdx.x;
    if (t < 32) { int o = t >> 2, c = t & 3; w1s[o][c] = (c < 3) ? w1g[o * 3 + c] : 0.f; }
    if (t < 8) bb1[t] = b1g[t];
    __syncthreads();

    float ps[16];
#pragma unroll
    for (int s = 0; s < 16; ++s) ps[s] = 0.f;
    int base = blockIdx.x * 1024 + t;
#pragma unroll
    for (int e = 0; e < 4; ++e) {
        int i = base + (e << 8);
        if (i < NEL) {
            int bq = i / VN;
            int v = i - bq * VN;
            float f0 = s_arr[i], f1 = mw_arr[i], f2 = lik[v];
#pragma unroll
            for (int o = 0; o < 8; ++o) {
                float4 wr = *(const float4*)&w1s[o][0];
                float z = bb1[o];
                z = fmaf(wr.x, f0, z);
                z = fmaf(wr.y, f1, z);
                z = fmaf(wr.z, f2, z);
                z = leaky1(z);
                ps[o] += z;
                ps[8 + o] += z * z;
            }
        }
    }
    int lane = t & 63, w = t >> 6;
#pragma unroll
    for (int s = 0; s < 16; ++s) {
        float v2 = ps[s];
        v2 += __shfl_xor(v2, 1);  v2 += __shfl_xor(v2, 2);  v2 += __shfl_xor(v2, 4);
        v2 += __shfl_xor(v2, 8);  v2 += __shfl_xor(v2, 16); v2 += __shfl_xor(v2, 32);
        if (lane == 0) lred[w][s] = v2;
    }
    __syncthreads();
    if (t < 16) part1[blockIdx.x * 16 + t] = lred[0][t] + lred[1][t] + lred[2][t] + lred[3][t];
}

// ---------------- K5: stat2 + fused fin1 prologue — 4-LANE-GROUP redesign ----------------
// History: channel-owned (16 lanes/element) was ~130us at every grid (r14/r15)
// and 261us with the r16 ticket: each wave-load covered only 4 distinct
// elements (16-way broadcast) + 16x redundant y1. Now: thread t = octet
// (t&3: 8 of 32 channels, weights in 16 float4 regs) x element-group (t>>2).
// Wave-load covers 16 distinct elements; y1 redundancy 4x; ps0/ps1[8] static.
// Grid NB2=512 chunk-stride (4 chunks) as in r14; part2 row layout unchanged.
__global__ __launch_bounds__(256) void k_stat2f(
        const float* __restrict__ s_arr, const float* __restrict__ mw_arr,
        const float* __restrict__ lik,
        const float* __restrict__ w1g, const float* __restrict__ b1g,
        const float* __restrict__ part1,
        const float* __restrict__ g1, const float* __restrict__ be1,
        const float* __restrict__ w2g, const float* __restrict__ b2g,
        float* __restrict__ scsh1g, float* __restrict__ part2) {
    int t = threadIdx.x;
    __shared__ double redd[256];
    __shared__ float sc1s[8], sh1s[8];
    __shared__ float sred[256][16];   // 16KB block-reduce tile
    {   // fin1 prologue (same reduction order as k_finalize<8>; r14-proven)
        int st = t & 15, gr = t >> 4;
        double acc = 0;
        for (int i = gr; i < NB_STAT; i += 16) acc += (double)part1[(size_t)i * 16 + st];
        redd[t] = acc;
        __syncthreads();
        if (t < 16) {
            double tot = redd[t];
            for (int g2 = 1; g2 < 16; ++g2) tot += redd[t + g2 * 16];
            redd[t] = tot;
        }
        __syncthreads();
        if (t < 8) {
            double mean = redd[t] / (double)NEL;
            double var = redd[8 + t] / (double)NEL - mean * mean;
            float r = (float)(1.0 / sqrt(var + 1e-5));
            float sc = g1[t] * r;
            float sh = be1[t] - (float)mean * sc;
            sc1s[t] = sc; sh1s[t] = sh;
            if (blockIdx.x == 0) { scsh1g[t] = sc; scsh1g[8 + t] = sh; }
        }
        __syncthreads();
    }
    int c4 = t & 3;          // channel octet: channels c4*8 .. c4*8+7
    int g  = t >> 2;         // element group 0..63

    float w1r[8][3], bb1[8], sc1[8], sh1[8];
#pragma unroll
    for (int o = 0; o < 8; ++o) {
        w1r[o][0] = w1g[o * 3];
        w1r[o][1] = w1g[o * 3 + 1];
        w1r[o][2] = w1g[o * 3 + 2];
        bb1[o] = b1g[o];
        sc1[o] = sc1s[o];
        sh1[o] = sh1s[o];
    }
    float4 w2a[8], w2b[8];
    float zb[8];
#pragma unroll
    for (int k = 0; k < 8; ++k) {
        int ch = c4 * 8 + k;
        w2a[k] = *(const float4*)(w2g + ch * 8);
        w2b[k] = *(const float4*)(w2g + ch * 8 + 4);
        zb[k] = b2g[ch];
    }

    float ps0[8], ps1[8];
#pragma unroll
    for (int k = 0; k < 8; ++k) { ps0[k] = 0.f; ps1[k] = 0.f; }

    for (int chunk = blockIdx.x; chunk < NB_STAT; chunk += NB2) {
        int base = chunk * 1024 + g;
        int vcur = base % VN;           // one div per chunk; elements step by 64
#pragma unroll 4
        for (int j = 0; j < 16; ++j) {
            int i = base + j * 64;
            if (i < NEL) {
                int v = vcur + j * 64;
                if (v >= VN) v -= VN;    // wraps at most once within a chunk
                float f0 = s_arr[i], f1 = mw_arr[i], f2 = lik[v];
                float y1[8];
#pragma unroll
                for (int o = 0; o < 8; ++o) {
                    float z = bb1[o];
                    z = fmaf(w1r[o][0], f0, z);
                    z = fmaf(w1r[o][1], f1, z);
                    z = fmaf(w1r[o][2], f2, z);
                    z = leaky1(z);
                    y1[o] = fmaf(z, sc1[o], sh1[o]);
                }
#pragma unroll
                for (int k = 0; k < 8; ++k) {
                    float z = zb[k];
                    z = fmaf(w2a[k].x, y1[0], z); z = fmaf(w2a[k].y, y1[1], z);
                    z = fmaf(w2a[k].z, y1[2], z); z = fmaf(w2a[k].w, y1[3], z);
                    z = fmaf(w2b[k].x, y1[4], z); z = fmaf(w2b[k].y, y1[5], z);
                    z = fmaf(w2b[k].z, y1[6], z); z = fmaf(w2b[k].w, y1[7], z);
                    z = leaky1(z);
                    ps0[k] += z; ps1[k] += z * z;
                }
            }
        }
    }
    // block reduce: sred[t][k]=sums, then [8+k]=sumsqs; output row [sum32|sumsq32]
#pragma unroll
    for (int k = 0; k < 8; ++k) { sred[t][k] = ps0[k]; sred[t][8 + k] = ps1[k]; }
    __syncthreads();
    if (t < 64) {
        int which = t >> 5;            // 0=sum, 1=sumsq
        int ch = t & 31;
        int o4 = ch >> 3, k = ch & 7;
        int slot = which * 8 + k;
        float s = 0.f;
        for (int j = 0; j < 64; ++j) s += sred[o4 + 4 * j][slot];
        part2[blockIdx.x * 64 + t] = s;
    }
}

// ---------------- K6: stat3 with FUSED fin2 prologue (r14, unchanged) ----------------
__global__ __launch_bounds__(256) void k_stat3f(
        const float* __restrict__ s_arr, const float* __restrict__ mw_arr,
        const float* __restrict__ lik,
        const float* __restrict__ w1g, const float* __restrict__ b1g,
        const float* __restrict__ scsh1g,
        const float* __restrict__ part2,
        const float* __restrict__ g2, const float* __restrict__ be2,
        const float* __restrict__ w2g, const float* __restrict__ b2g,
        const float* __restrict__ w3g, const float* __restrict__ b3g,
        float* __restrict__ scsh2g, float* __restrict__ part3) {
    int t = threadIdx.x;
    __shared__ double redd[256];
    __shared__ double tot64[64];
    __shared__ __align__(16) float w1s[8][4];
    __shared__ __align__(16) float w2s[32][8];
    __shared__ __align__(16) float w3t[32][8];
    __shared__ float bb1[8], sc1[8], sh1[8];
    __shared__ float bb2[32], sc2[32], sh2[32];
    __shared__ float bb3[8];
    __shared__ float lred[4][16];

    {   // fin2 prologue from part2 [NB2][64]
        int st = t & 63, gr = t >> 6;   // 4 groups
        double acc = 0;
        for (int i = gr; i < NB2; i += 4) acc += (double)part2[(size_t)i * 64 + st];
        redd[t] = acc;
        __syncthreads();
        if (t < 64) tot64[t] = redd[t] + redd[t + 64] + redd[t + 128] + redd[t + 192];
        __syncthreads();
        if (t < 32) {
            double mean = tot64[t] / (double)NEL;
            double var = tot64[32 + t] / (double)NEL - mean * mean;
            float r = (float)(1.0 / sqrt(var + 1e-5));
            float sc = g2[t] * r;
            float sh = be2[t] - (float)mean * sc;
            sc2[t] = sc; sh2[t] = sh; bb2[t] = b2g[t];
            if (blockIdx.x == 0) { scsh2g[t] = sc; scsh2g[32 + t] = sh; }
        }
    }
    if (t < 32) { int o = t >> 2, c = t & 3; w1s[o][c] = (c < 3) ? w1g[o * 3 + c] : 0.f; }
    if (t < 8) { bb1[t] = b1g[t]; sc1[t] = scsh1g[t]; sh1[t] = scsh1g[8 + t]; bb3[t] = b3g[t]; }
    if (t < 256) { w2s[t >> 3][t & 7] = w2g[t]; w3t[t & 31][t >> 5] = w3g[t]; }
    __syncthreads();

    float ps[16];
#pragma unroll
    for (int s = 0; s < 16; ++s) ps[s] = 0.f;

    for (int chunk = blockIdx.x; chunk < NB_STAT; chunk += NB2) {
        int base = chunk * 1024 + t;
        bool ok[4];
        float y1[8][4];
#pragma unroll
        for (int e = 0; e < 4; ++e) {
            int i = base + (e << 8);
            ok[e] = (i < NEL);
            float f0 = 0.f, f1 = 0.f, f2 = 0.f;
            if (ok[e]) {
                int bq = i / VN; int v = i - bq * VN;
                f0 = s_arr[i]; f1 = mw_arr[i]; f2 = lik[v];
            }
#pragma unroll
            for (int o = 0; o < 8; ++o) {
                float4 wr = *(const float4*)&w1s[o][0];
                float z = bb1[o];
                z = fmaf(wr.x, f0, z); z = fmaf(wr.y, f1, z); z = fmaf(wr.z, f2, z);
                z = leaky1(z);
                y1[o][e] = fmaf(z, sc1[o], sh1[o]);
            }
        }
        float z3[8][4];
#pragma unroll
        for (int o3 = 0; o3 < 8; ++o3) {
            float bv = bb3[o3];
#pragma unroll
            for (int e = 0; e < 4; ++e) z3[o3][e] = bv;
        }
#pragma unroll 4
        for (int o = 0; o < 32; ++o) {
            float4 wa = *(const float4*)&w2s[o][0];
            float4 wb = *(const float4*)&w2s[o][4];
            float4 ua = *(const float4*)&w3t[o][0];
            float4 ub = *(const float4*)&w3t[o][4];
            float zb = bb2[o], sc = sc2[o], sh = sh2[o];
#pragma unroll
            for (int e = 0; e < 4; ++e) {
                float z = zb;
                z = fmaf(wa.x, y1[0][e], z); z = fmaf(wa.y, y1[1][e], z);
                z = fmaf(wa.z, y1[2][e], z); z = fmaf(wa.w, y1[3][e], z);
                z = fmaf(wb.x, y1[4][e], z); z = fmaf(wb.y, y1[5][e], z);
                z = fmaf(wb.z, y1[6][e], z); z = fmaf(wb.w, y1[7][e], z);
                z = leaky1(z);
                float y2 = fmaf(z, sc, sh);
                z3[0][e] = fmaf(ua.x, y2, z3[0][e]);
                z3[1][e] = fmaf(ua.y, y2, z3[1][e]);
                z3[2][e] = fmaf(ua.z, y2, z3[2][e]);
                z3[3][e] = fmaf(ua.w, y2, z3[3][e]);
                z3[4][e] = fmaf(ub.x, y2, z3[4][e]);
                z3[5][e] = fmaf(ub.y, y2, z3[5][e]);
                z3[6][e] = fmaf(ub.z, y2, z3[6][e]);
                z3[7][e] = fmaf(ub.w, y2, z3[7][e]);
            }
        }
#pragma unroll
        for (int e = 0; e < 4; ++e) {
            if (!ok[e]) continue;
#pragma unroll
            for (int o3 = 0; o3 < 8; ++o3) {
                float z = leaky1(z3[o3][e]);
                ps[o3] += z;
                ps[8 + o3] += z * z;
            }
        }
    }
    int lane = t & 63, w = t >> 6;
#pragma unroll
    for (int s = 0; s < 16; ++s) {
        float v2 = ps[s];
        v2 += __shfl_xor(v2, 1);  v2 += __shfl_xor(v2, 2);  v2 += __shfl_xor(v2, 4);
        v2 += __shfl_xor(v2, 8);  v2 += __shfl_xor(v2, 16); v2 += __shfl_xor(v2, 32);
        if (lane == 0) lred[w][s] = v2;
    }
    __syncthreads();
    if (t < 16) part3[blockIdx.x * 16 + t] = lred[0][t] + lred[1][t] + lred[2][t] + lred[3][t];
}

// ---------------- K7: output with FUSED fin3 prologue (r14, unchanged) ----------------
__global__ __launch_bounds__(256) void k_outf(
        const float* __restrict__ s_arr, const float* __restrict__ mw_arr,
        const float* __restrict__ lik,
        const float* __restrict__ w1g, const float* __restrict__ b1g,
        const float* __restrict__ scsh1g,
        const float* __restrict__ w2g, const float* __restrict__ b2g,
        const float* __restrict__ scsh2g,
        const float* __restrict__ w3g, const float* __restrict__ b3g,
        const float* __restrict__ part3,
        const float* __restrict__ g3, const float* __restrict__ be3,
        const float* __restrict__ w4g, const float* __restrict__ b4g,
        float* __restrict__ outp) {
    int t = threadIdx.x;
    __shared__ double redd[256];
    __shared__ __align__(16) float w1s[8][4];
    __shared__ __align__(16) float w2s[32][8];
    __shared__ __align__(16) float w3t[32][8];
    __shared__ float bb1[8], sc1[8], sh1[8];
    __shared__ float bb2[32], sc2[32], sh2[32];
    __shared__ float bb3[8], sc3[8], sh3[8], w4s[8];
    __shared__ float bb4s;

    {   // fin3 prologue from part3 [NB2][16]
        int st = t & 15, gr = t >> 4;
        double acc = 0;
        for (int i = gr; i < NB2; i += 16) acc += (double)part3[(size_t)i * 16 + st];
        redd[t] = acc;
        __syncthreads();
        if (t < 16) {
            double tot = redd[t];
            for (int g2i = 1; g2i < 16; ++g2i) tot += redd[t + g2i * 16];
            redd[t] = tot;
        }
        __syncthreads();
        if (t < 8) {
            double mean = redd[t] / (double)NEL;
            double var = redd[8 + t] / (double)NEL - mean * mean;
            float r = (float)(1.0 / sqrt(var + 1e-5));
            float sc = g3[t] * r;
            float sh = be3[t] - (float)mean * sc;
            sc3[t] = sc; sh3[t] = sh;
        }
    }
    if (t < 32) { int o = t >> 2, c = t & 3; w1s[o][c] = (c < 3) ? w1g[o * 3 + c] : 0.f; }
    if (t < 8) {
        bb1[t] = b1g[t]; sc1[t] = scsh1g[t]; sh1[t] = scsh1g[8 + t];
        bb3[t] = b3g[t]; w4s[t] = w4g[t];
    }
    if (t < 256) { w2s[t >> 3][t & 7] = w2g[t]; w3t[t & 31][t >> 5] = w3g[t]; }
    if (t < 32) { bb2[t] = b2g[t]; sc2[t] = scsh2g[t]; sh2[t] = scsh2g[32 + t]; }
    if (t == 0) bb4s = b4g[0];
    __syncthreads();

    int base = blockIdx.x * 1024 + t;
    bool ok[4];
    float y1[8][4];
#pragma unroll
    for (int e = 0; e < 4; ++e) {
        int i = base + (e << 8);
        ok[e] = (i < NEL);
        float f0 = 0.f, f1 = 0.f, f2 = 0.f;
        if (ok[e]) {
            int bq = i / VN; int v = i - bq * VN;
            f0 = s_arr[i]; f1 = mw_arr[i]; f2 = lik[v];
        }
#pragma unroll
        for (int o = 0; o < 8; ++o) {
            float4 wr = *(const float4*)&w1s[o][0];
            float z = bb1[o];
            z = fmaf(wr.x, f0, z); z = fmaf(wr.y, f1, z); z = fmaf(wr.z, f2, z);
            z = leaky1(z);
            y1[o][e] = fmaf(z, sc1[o], sh1[o]);
        }
    }
    float z3[8][4];
#pragma unroll
    for (int o3 = 0; o3 < 8; ++o3) {
        float bv = bb3[o3];
#pragma unroll
        for (int e = 0; e < 4; ++e) z3[o3][e] = bv;
    }
#pragma unroll 4
    for (int o = 0; o < 32; ++o) {
        float4 wa = *(const float4*)&w2s[o][0];
        float4 wb = *(const float4*)&w2s[o][4];
        float4 ua = *(const float4*)&w3t[o][0];
        float4 ub = *(const float4*)&w3t[o][4];
        float zb = bb2[o], sc = sc2[o], sh = sh2[o];
#pragma unroll
        for (int e = 0; e < 4; ++e) {
            float z = zb;
            z = fmaf(wa.x, y1[0][e], z); z = fmaf(wa.y, y1[1][e], z);
            z = fmaf(wa.z, y1[2][e], z); z = fmaf(wa.w, y1[3][e], z);
            z = fmaf(wb.x, y1[4][e], z); z = fmaf(wb.y, y1[5][e], z);
            z = fmaf(wb.z, y1[6][e], z); z = fmaf(wb.w, y1[7][e], z);
            z = leaky1(z);
            float y2 = fmaf(z, sc, sh);
            z3[0][e] = fmaf(ua.x, y2, z3[0][e]);
            z3[1][e] = fmaf(ua.y, y2, z3[1][e]);
            z3[2][e] = fmaf(ua.z, y2, z3[2][e]);
            z3[3][e] = fmaf(ua.w, y2, z3[3][e]);
            z3[4][e] = fmaf(ub.x, y2, z3[4][e]);
            z3[5][e] = fmaf(ub.y, y2, z3[5][e]);
            z3[6][e] = fmaf(ub.z, y2, z3[6][e]);
            z3[7][e] = fmaf(ub.w, y2, z3[7][e]);
        }
    }
#pragma unroll
    for (int e = 0; e < 4; ++e) {
        if (!ok[e]) continue;
        float oacc = bb4s;
#pragma unroll
        for (int o3 = 0; o3 < 8; ++o3) {
            float z = leaky1(z3[o3][e]);
            float y3 = fmaf(z, sc3[o3], sh3[o3]);
            oacc = fmaf(w4s[o3], y3, oacc);
        }
        outp[base + (e << 8)] = oacc;
    }
}

extern "C" void kernel_launch(void* const* d_in, const int* in_sizes, int n_in,
                              void* d_out, int out_size, void* d_ws, size_t ws_size,
                              hipStream_t stream) {
    const int*   hist = (const int*)d_in[0];
    const float* week = (const float*)d_in[1];
    const float* emb  = (const float*)d_in[2];
    const float* lik  = (const float*)d_in[3];
    const float* w1 = (const float*)d_in[4];
    const float* b1 = (const float*)d_in[5];
    const float* g1 = (const float*)d_in[6];
    const float* be1 = (const float*)d_in[7];
    const float* w2 = (const float*)d_in[8];
    const float* b2 = (const float*)d_in[9];
    const float* g2 = (const float*)d_in[10];
    const float* be2 = (const float*)d_in[11];
    const float* w3 = (const float*)d_in[12];
    const float* b3 = (const float*)d_in[13];
    const float* g3 = (const float*)d_in[14];
    const float* be3 = (const float*)d_in[15];
    const float* w4 = (const float*)d_in[16];
    const float* b4 = (const float*)d_in[17];
    float* outp = (float*)d_out;
    char* ws = (char*)d_ws;

    unsigned* cnt   = (unsigned*)(ws + OFF_CNT);
    unsigned* flags = (unsigned*)(ws + OFF_FLAG);
    float* rnorm = (float*)(ws + OFF_RNORM);
    double* rqd  = (double*)(ws + OFF_RQD);
    float* QgT   = (float*)(ws + OFF_QG);
    float* s_arr = (float*)(ws + OFF_S);
    float* mw    = (float*)(ws + OFF_MW);
    float* part1 = (float*)(ws + OFF_PART1);
    float* part2 = (float*)(ws + OFF_PART2);
    float* part3 = (float*)(ws + OFF_PART3);
    float* scsh1 = (float*)(ws + OFF_SCSH1);
    float* scsh2 = (float*)(ws + OFF_SCSH2);
    unsigned short* embh = (unsigned short*)(ws + OFF_EMBH);
    unsigned short* embl = (unsigned short*)(ws + OFF_EMBL);
    unsigned short* Qhp  = (unsigned short*)(ws + OFF_QH);
    unsigned short* Qlp  = (unsigned short*)(ws + OFF_QL);

    k_prep<<<25256, 256, 0, stream>>>(emb, hist, rnorm, embh, embl, QgT, rqd, Qhp, Qlp, cnt);
    k_sims<<<NBLK_SIMS, 512, 0, stream>>>(embh, embl, Qhp, Qlp, rnorm, week, s_arr, mw, cnt, flags);
    k_fixup<<<1024, 256, 0, stream>>>(emb, QgT, rqd, week, cnt, flags, mw);
    k_stat1<<<NB_STAT, 256, 0, stream>>>(s_arr, mw, lik, w1, b1, part1);
    k_stat2f<<<NB2, 256, 0, stream>>>(s_arr, mw, lik, w1, b1, part1, g1, be1, w2, b2, scsh1, part2);
    k_stat3f<<<NB2, 256, 0, stream>>>(s_arr, mw, lik, w1, b1, scsh1, part2, g2, be2, w2, b2, w3, b3, scsh2, part3);
    k_outf<<<NB_STAT, 256, 0, stream>>>(s_arr, mw, lik, w1, b1, scsh1, w2, b2, scsh2, w3, b3, part3, g3, be3, w4, b4, outp);
    (void)in_sizes; (void)n_in; (void)out_size; (void)ws_size;
}

// Round 18
// 305.857 us; speedup vs baseline: 2.1809x; 1.0138x over previous
//
#include <hip/hip_runtime.h>
#include <math.h>

#define VN 100000
#define DD 128
#define BBATCH 16
#define HH 64
#define NEL (BBATCH*VN)   // 1,600,000
#define NB_STAT 1563      // chunks of 1024
#define NB2 512           // stat2/stat3 grid (chunk-stride)
#define NVGRP 196
#define NBLK_SIMS (16*NVGRP)  // 3136, divisible by 8
#define NB_PREP 12756     // 12500 rownorm (2 rows/wave) + 256 gather

#define FLAG_CAP 262144u
#define FLAG_EPS 4e-5f

// ---- workspace layout (bytes) ----
#define OFF_CNT    0
#define OFF_FLAG   1024
#define OFF_RNORM  (OFF_FLAG + FLAG_CAP*4)
#define OFF_RQD    (OFF_RNORM + VN*4)
#define OFF_QG     (OFF_RQD + 1024*8)          // QgT (fp32, b x k x h = 512KB)
#define OFF_S      (OFF_QG + 1024*DD*4)
#define OFF_MW     (OFF_S + NEL*4)
#define OFF_PART1  (OFF_MW + NEL*4)            // 1563*16*4
#define OFF_PART2  (OFF_PART1 + NB_STAT*16*4)  // 512*64*4
#define OFF_PART3  (OFF_PART2 + NB2*64*4)      // 512*16*4
#define OFF_SCSH1  (OFF_PART3 + NB2*16*4)
#define OFF_SCSH2  (OFF_SCSH1 + 256)
#define OFF_EMBH   ((size_t)(OFF_SCSH2 + 256))
#define OFF_EMBL   (OFF_EMBH + (size_t)VN*DD*2)
#define OFF_QH     (OFF_EMBL + (size_t)VN*DD*2)
#define OFF_QL     (OFF_QH + (size_t)1024*DD*2)

typedef __attribute__((ext_vector_type(8))) short short8;
typedef __attribute__((ext_vector_type(16))) float f32x16;

__device__ __forceinline__ float leaky1(float x) { return x >= 0.f ? x : 0.01f * x; }

__device__ __forceinline__ unsigned short f2bf(float f) {
    unsigned u = __float_as_uint(f);
    u += 0x7fffu + ((u >> 16) & 1u);
    return (unsigned short)(u >> 16);
}
__device__ __forceinline__ float bf2f(unsigned short s) {
    return __uint_as_float(((unsigned)s) << 16);
}

// ---------------- K1: prep = cnt-zero + rownorm (2 rows/wave, float4) + gather/dedupe ----------------
// r18: rownorm moved from 1 row/wave (float2 lanes, 8B) to 2 rows/wave with
// float4 lanes (16B = coalescing sweet spot, G13); 50000 waves, 12500 blocks.
// Identical arithmetic (RNE bf16 split, fp64 norm) -> bit-identical outputs.
__global__ __launch_bounds__(256) void k_prep(
        const float* __restrict__ emb, const int* __restrict__ hist,
        float* __restrict__ rnorm,
        unsigned short* __restrict__ embh, unsigned short* __restrict__ embl,
        float* __restrict__ QgT, double* __restrict__ rqd,
        unsigned short* __restrict__ Qh, unsigned short* __restrict__ Ql,
        unsigned* __restrict__ cnt) {
    int bid = blockIdx.x;
    int t = threadIdx.x;
    int lane = t & 63;
    if (bid < 12500) {
        int wgl = (bid * 256 + t) >> 6;       // global wave id 0..49999
        int half = lane >> 5;                 // 0/1 -> which of the 2 rows
        int l32 = lane & 31;
        int row = wgl * 2 + half;             // < 100000 always
        const float* rp = emb + (size_t)row * DD;
        float4 a = ((const float4*)rp)[l32];
        unsigned short h0 = f2bf(a.x), h1 = f2bf(a.y), h2 = f2bf(a.z), h3 = f2bf(a.w);
        unsigned short l0 = f2bf(a.x - bf2f(h0)), l1 = f2bf(a.y - bf2f(h1));
        unsigned short l2 = f2bf(a.z - bf2f(h2)), l3 = f2bf(a.w - bf2f(h3));
        ushort4 hv; hv.x = h0; hv.y = h1; hv.z = h2; hv.w = h3;
        ushort4 lv; lv.x = l0; lv.y = l1; lv.z = l2; lv.w = l3;
        *(ushort4*)(embh + (size_t)row * DD + l32 * 4) = hv;
        *(ushort4*)(embl + (size_t)row * DD + l32 * 4) = lv;
        double ss = (double)a.x * a.x + (double)a.y * a.y
                  + (double)a.z * a.z + (double)a.w * a.w;
        ss += __shfl_xor(ss, 1);  ss += __shfl_xor(ss, 2);  ss += __shfl_xor(ss, 4);
        ss += __shfl_xor(ss, 8);  ss += __shfl_xor(ss, 16);
        if (l32 == 0) {
            double n = sqrt(ss);
            if (n < 1e-12) n = 1e-12;
            rnorm[row] = (float)(1.0 / n);
        }
    } else {
        if (bid == 12500 && t == 0) *cnt = 0;
        int gid = (bid - 12500) * 256 + t;
        int wid = gid >> 6;
        if (wid >= BBATCH * HH) return;
        int b = wid >> 6, h = wid & 63;
        int a = hist[wid];
        int hl = hist[(b << 6) + lane];
        unsigned long long m = __ballot((lane < h) && (hl == a));
        bool dup = (m != 0ull);
        const float* row = emb + (size_t)a * DD;
        float2 tv = *(const float2*)(row + lane * 2);
        QgT[((size_t)b * DD + 2 * lane) * 64 + h] = tv.x;
        QgT[((size_t)b * DD + 2 * lane + 1) * 64 + h] = tv.y;
        double ss = (double)tv.x * tv.x + (double)tv.y * tv.y;
        ss += __shfl_xor(ss, 1);  ss += __shfl_xor(ss, 2);  ss += __shfl_xor(ss, 4);
        ss += __shfl_xor(ss, 8);  ss += __shfl_xor(ss, 16); ss += __shfl_xor(ss, 32);
        double n = sqrt(ss);
        if (n < 1e-12) n = 1e-12;
        double r = 1.0 / n;
        float rf = (float)r;
        float sx = tv.x * rf, sy = tv.y * rf;
        unsigned short h0 = f2bf(sx), h1 = f2bf(sy);
        unsigned short l0 = f2bf(sx - bf2f(h0)), l1 = f2bf(sy - bf2f(h1));
        ushort2 hv, lv;
        if (dup) { hv.x = 0; hv.y = 0; lv.x = 0; lv.y = 0; }
        else     { hv.x = h0; hv.y = h1; lv.x = l0; lv.y = l1; }
        *(ushort2*)(Qh + (size_t)wid * DD + lane * 2) = hv;
        *(ushort2*)(Ql + (size_t)wid * DD + lane * 2) = lv;
        if (lane == 0) rqd[wid] = r;
    }
}

// ---------------- K2: MFMA 32x32x16 sims (r11 version, unchanged) ----------------
__global__ __launch_bounds__(512) void k_sims(
        const unsigned short* __restrict__ embh, const unsigned short* __restrict__ embl,
        const unsigned short* __restrict__ Qh, const unsigned short* __restrict__ Ql,
        const float* __restrict__ rnorm, const float* __restrict__ week,
        float* __restrict__ s_arr, float* __restrict__ mw_arr,
        unsigned* __restrict__ cnt, unsigned* __restrict__ flags) {
    int bid = blockIdx.x;
    int logical = (bid & 7) * (NBLK_SIMS / 8) + (bid >> 3);
    int b = logical & 15;
    int vgroup = logical >> 4;
    int t = threadIdx.x;
    int w = t >> 6;
    int lane = t & 63;
    int l31 = lane & 31, l5 = lane >> 5;

    __shared__ unsigned short qlds[2][64 * 128];

    for (int i = 0; i < 2; ++i) {
        int c = t + (i << 9);
        int row = c >> 4, cc = c & 15;
        size_t g = (size_t)(b * 64 + row) * DD + cc * 8;
        unsigned off = (unsigned)((row * 256 + cc * 16)) ^ (unsigned)((row & 7) << 4);
        *(short8*)((char*)&qlds[0][0] + off) = *(const short8*)(Qh + g);
        *(short8*)((char*)&qlds[1][0] + off) = *(const short8*)(Ql + g);
    }
    __syncthreads();

    int vb = vgroup * 512 + w * 64;

    size_t eoff[2];
#pragma unroll
    for (int bt = 0; bt < 2; ++bt) {
        int v = vb + bt * 32 + l31;
        int vc = v < VN ? v : VN - 1;
        eoff[bt] = (size_t)vc * DD + l5 * 8;
    }

    f32x16 acc[2][2];
#pragma unroll
    for (int bt = 0; bt < 2; ++bt)
#pragma unroll
        for (int ht = 0; ht < 2; ++ht)
#pragma unroll
            for (int r = 0; r < 16; ++r) acc[bt][ht][r] = 0.f;

    short8 Bhb[3][2], Blb[3][2];
#pragma unroll
    for (int bt = 0; bt < 2; ++bt) {
        Bhb[0][bt] = *(const short8*)(embh + eoff[bt]);
        Blb[0][bt] = *(const short8*)(embl + eoff[bt]);
    }
#pragma unroll
    for (int bt = 0; bt < 2; ++bt) {
        Bhb[1][bt] = *(const short8*)(embh + eoff[bt] + 16);
        Blb[1][bt] = *(const short8*)(embl + eoff[bt] + 16);
    }

#pragma unroll
    for (int s = 0; s < 8; ++s) {
        const int cur = s % 3;
        if (s < 6) {
            const int pf = (s + 2) % 3;
#pragma unroll
            for (int bt = 0; bt < 2; ++bt) {
                Bhb[pf][bt] = *(const short8*)(embh + eoff[bt] + (s + 2) * 16);
                Blb[pf][bt] = *(const short8*)(embl + eoff[bt] + (s + 2) * 16);
            }
        }
        short8 Ah[2], Al[2];
#pragma unroll
        for (int ht = 0; ht < 2; ++ht) {
            int row = ht * 32 + l31;
            unsigned off = (unsigned)(row * 256 + s * 32 + l5 * 16) ^ (unsigned)((row & 7) << 4);
            Ah[ht] = *(const short8*)((const char*)&qlds[0][0] + off);
            Al[ht] = *(const short8*)((const char*)&qlds[1][0] + off);
        }
#pragma unroll
        for (int bt = 0; bt < 2; ++bt) {
#pragma unroll
            for (int ht = 0; ht < 2; ++ht) {
                acc[bt][ht] = __builtin_amdgcn_mfma_f32_32x32x16_bf16(Ah[ht], Bhb[cur][bt], acc[bt][ht], 0, 0, 0);
                acc[bt][ht] = __builtin_amdgcn_mfma_f32_32x32x16_bf16(Al[ht], Bhb[cur][bt], acc[bt][ht], 0, 0, 0);
                acc[bt][ht] = __builtin_amdgcn_mfma_f32_32x32x16_bf16(Ah[ht], Blb[cur][bt], acc[bt][ht], 0, 0, 0);
            }
        }
    }

#pragma unroll
    for (int bt = 0; bt < 2; ++bt) {
        float m1 = -1e30f, m2 = -1e30f;
        int i1 = 0;
#pragma unroll
        for (int ht = 0; ht < 2; ++ht) {
#pragma unroll
            for (int r = 0; r < 16; ++r) {
                float val = acc[bt][ht][r];
                int h = ht * 32 + (r & 3) + 8 * (r >> 2) + 4 * l5;
                if (val > m1) { m2 = m1; m1 = val; i1 = h; }
                else if (val > m2) m2 = val;
            }
        }
        {
            float o1 = __shfl_xor(m1, 32);
            float o2 = __shfl_xor(m2, 32);
            int   oi = __shfl_xor(i1, 32);
            if (o1 > m1) { m2 = fmaxf(m1, o2); m1 = o1; i1 = oi; }
            else         { m2 = fmaxf(m2, o1); }
        }
        if (lane < 32) {
            int v = vb + bt * 32 + lane;
            if (v < VN) {
                float re = rnorm[v];
                float sv = m1 * re;
                float gap = (m1 - m2) * re;
                if (gap < FLAG_EPS) {
                    unsigned idx = atomicAdd(cnt, 1u);
                    if (idx < FLAG_CAP) flags[idx] = (unsigned)(b * VN + v);
                }
                float sc = fminf(fmaxf(sv, 0.001f), 0.999f);
                float logit = -logf(1.0f / sc - 1.0f);
                int i = b * VN + v;
                s_arr[i] = logit;
                mw_arr[i] = week[b * HH + i1];
            }
        }
    }
}

// ---------------- K3: h-parallel fp64 fixup (r11, unchanged) ----------------
__global__ __launch_bounds__(256) void k_fixup(
        const float* __restrict__ emb, const float* __restrict__ QgT,
        const double* __restrict__ rqd, const float* __restrict__ week,
        const unsigned* __restrict__ cnt, const unsigned* __restrict__ flags,
        float* __restrict__ mw_arr) {
    unsigned n = *cnt;
    if (n > FLAG_CAP) n = FLAG_CAP;
    int lane = threadIdx.x & 63;
    unsigned wid = (blockIdx.x * blockDim.x + threadIdx.x) >> 6;
    unsigned nw = (gridDim.x * blockDim.x) >> 6;
    for (unsigned x = wid; x < n; x += nw) {
        unsigned i = flags[x];
        int b = (int)(i / VN);
        int v = (int)(i - (unsigned)b * VN);
        const float* e = emb + (size_t)v * DD;
        const float* qT = QgT + (size_t)b * DD * 64;
        double s0 = 0, s1 = 0, s2 = 0, s3 = 0;
        for (int k = 0; k < DD; k += 4) {
            float4 ev = *(const float4*)(e + k);
            s0 += (double)ev.x * (double)qT[(k    ) * 64 + lane];
            s1 += (double)ev.y * (double)qT[(k + 1) * 64 + lane];
            s2 += (double)ev.z * (double)qT[(k + 2) * 64 + lane];
            s3 += (double)ev.w * (double)qT[(k + 3) * 64 + lane];
        }
        double sim = ((s0 + s1) + (s2 + s3)) * rqd[b * 64 + lane];
        int bh = lane;
#pragma unroll
        for (int mask = 1; mask <= 32; mask <<= 1) {
            double o = __shfl_xor(sim, mask);
            int oh = __shfl_xor(bh, mask);
            if (o > sim || (o == sim && oh < bh)) { sim = o; bh = oh; }
        }
        if (lane == 0) mw_arr[i] = week[b * HH + bh];
    }
}

// ---------------- K4: layer-1 stats (r11, unchanged) ----------------
__global__ __launch_bounds__(256) void k_stat1(
        const float* __restrict__ s_arr, const float* __restrict__ mw_arr,
        const float* __restrict__ lik,
        const float* __restrict__ w1g, const float* __restrict__ b1g,
        float* __restrict__ part1) {
    __shared__ __align__(16) float w1s[8][4];
    __shared__ float bb1[8];
    __shared__ float lred[4][16];
    int t = threadIdx.x;
    if (t < 32) { int o = t >> 2, c = t & 3; w1s[o][c] = (c < 3) ? w1g[o * 3 + c] : 0.f; }
    if (t < 8) bb1[t] = b1g[t];
    __syncthreads();

    float ps[16];
#pragma unroll
    for (int s = 0; s < 16; ++s) ps[s] = 0.f;
    int base = blockIdx.x * 1024 + t;
#pragma unroll
    for (int e = 0; e < 4; ++e) {
        int i = base + (e << 8);
        if (i < NEL) {
            int bq = i / VN;
            int v = i - bq * VN;
            float f0 = s_arr[i], f1 = mw_arr[i], f2 = lik[v];
#pragma unroll
            for (int o = 0; o < 8; ++o) {
                float4 wr = *(const float4*)&w1s[o][0];
                float z = bb1[o];
                z = fmaf(wr.x, f0, z);
                z = fmaf(wr.y, f1, z);
                z = fmaf(wr.z, f2, z);
                z = leaky1(z);
                ps[o] += z;
                ps[8 + o] += z * z;
            }
        }
    }
    int lane = t & 63, w = t >> 6;
#pragma unroll
    for (int s = 0; s < 16; ++s) {
        float v2 = ps[s];
        v2 += __shfl_xor(v2, 1);  v2 += __shfl_xor(v2, 2);  v2 += __shfl_xor(v2, 4);
        v2 += __shfl_xor(v2, 8);  v2 += __shfl_xor(v2, 16); v2 += __shfl_xor(v2, 32);
        if (lane == 0) lred[w][s] = v2;
    }
    __syncthreads();
    if (t < 16) part1[blockIdx.x * 16 + t] = lred[0][t] + lred[1][t] + lred[2][t] + lred[3][t];
}

// ---------------- K5: stat2 + fused fin1 prologue — 4-lane-group (r17, unchanged) ----------------
__global__ __launch_bounds__(256) void k_stat2f(
        const float* __restrict__ s_arr, const float* __restrict__ mw_arr,
        const float* __restrict__ lik,
        const float* __restrict__ w1g, const float* __restrict__ b1g,
        const float* __restrict__ part1,
        const float* __restrict__ g1, const float* __restrict__ be1,
        const float* __restrict__ w2g, const float* __restrict__ b2g,
        float* __restrict__ scsh1g, float* __restrict__ part2) {
    int t = threadIdx.x;
    __shared__ double redd[256];
    __shared__ float sc1s[8], sh1s[8];
    __shared__ float sred[256][16];   // 16KB block-reduce tile
    {   // fin1 prologue (same reduction order as k_finalize<8>; r14-proven)
        int st = t & 15, gr = t >> 4;
        double acc = 0;
        for (int i = gr; i < NB_STAT; i += 16) acc += (double)part1[(size_t)i * 16 + st];
        redd[t] = acc;
        __syncthreads();
        if (t < 16) {
            double tot = redd[t];
            for (int g2 = 1; g2 < 16; ++g2) tot += redd[t + g2 * 16];
            redd[t] = tot;
        }
        __syncthreads();
        if (t < 8) {
            double mean = redd[t] / (double)NEL;
            double var = redd[8 + t] / (double)NEL - mean * mean;
            float r = (float)(1.0 / sqrt(var + 1e-5));
            float sc = g1[t] * r;
            float sh = be1[t] - (float)mean * sc;
            sc1s[t] = sc; sh1s[t] = sh;
            if (blockIdx.x == 0) { scsh1g[t] = sc; scsh1g[8 + t] = sh; }
        }
        __syncthreads();
    }
    int c4 = t & 3;          // channel octet: channels c4*8 .. c4*8+7
    int g  = t >> 2;         // element group 0..63

    float w1r[8][3], bb1[8], sc1[8], sh1[8];
#pragma unroll
    for (int o = 0; o < 8; ++o) {
        w1r[o][0] = w1g[o * 3];
        w1r[o][1] = w1g[o * 3 + 1];
        w1r[o][2] = w1g[o * 3 + 2];
        bb1[o] = b1g[o];
        sc1[o] = sc1s[o];
        sh1[o] = sh1s[o];
    }
    float4 w2a[8], w2b[8];
    float zb[8];
#pragma unroll
    for (int k = 0; k < 8; ++k) {
        int ch = c4 * 8 + k;
        w2a[k] = *(const float4*)(w2g + ch * 8);
        w2b[k] = *(const float4*)(w2g + ch * 8 + 4);
        zb[k] = b2g[ch];
    }

    float ps0[8], ps1[8];
#pragma unroll
    for (int k = 0; k < 8; ++k) { ps0[k] = 0.f; ps1[k] = 0.f; }

    for (int chunk = blockIdx.x; chunk < NB_STAT; chunk += NB2) {
        int base = chunk * 1024 + g;
        int vcur = base % VN;           // one div per chunk; elements step by 64
#pragma unroll 4
        for (int j = 0; j < 16; ++j) {
            int i = base + j * 64;
            if (i < NEL) {
                int v = vcur + j * 64;
                if (v >= VN) v -= VN;    // wraps at most once within a chunk
                float f0 = s_arr[i], f1 = mw_arr[i], f2 = lik[v];
                float y1[8];
#pragma unroll
                for (int o = 0; o < 8; ++o) {
                    float z = bb1[o];
                    z = fmaf(w1r[o][0], f0, z);
                    z = fmaf(w1r[o][1], f1, z);
                    z = fmaf(w1r[o][2], f2, z);
                    z = leaky1(z);
                    y1[o] = fmaf(z, sc1[o], sh1[o]);
                }
#pragma unroll
                for (int k = 0; k < 8; ++k) {
                    float z = zb[k];
                    z = fmaf(w2a[k].x, y1[0], z); z = fmaf(w2a[k].y, y1[1], z);
                    z = fmaf(w2a[k].z, y1[2], z); z = fmaf(w2a[k].w, y1[3], z);
                    z = fmaf(w2b[k].x, y1[4], z); z = fmaf(w2b[k].y, y1[5], z);
                    z = fmaf(w2b[k].z, y1[6], z); z = fmaf(w2b[k].w, y1[7], z);
                    z = leaky1(z);
                    ps0[k] += z; ps1[k] += z * z;
                }
            }
        }
    }
    // block reduce: sred[t][k]=sums, then [8+k]=sumsqs; output row [sum32|sumsq32]
#pragma unroll
    for (int k = 0; k < 8; ++k) { sred[t][k] = ps0[k]; sred[t][8 + k] = ps1[k]; }
    __syncthreads();
    if (t < 64) {
        int which = t >> 5;            // 0=sum, 1=sumsq
        int ch = t & 31;
        int o4 = ch >> 3, k = ch & 7;
        int slot = which * 8 + k;
        float s = 0.f;
        for (int j = 0; j < 64; ++j) s += sred[o4 + 4 * j][slot];
        part2[blockIdx.x * 64 + t] = s;
    }
}

// ---------------- K6: stat3 with FUSED fin2 prologue (r14, unchanged) ----------------
__global__ __launch_bounds__(256) void k_stat3f(
        const float* __restrict__ s_arr, const float* __restrict__ mw_arr,
        const float* __restrict__ lik,
        const float* __restrict__ w1g, const float* __restrict__ b1g,
        const float* __restrict__ scsh1g,
        const float* __restrict__ part2,
        const float* __restrict__ g2, const float* __restrict__ be2,
        const float* __restrict__ w2g, const float* __restrict__ b2g,
        const float* __restrict__ w3g, const float* __restrict__ b3g,
        float* __restrict__ scsh2g, float* __restrict__ part3) {
    int t = threadIdx.x;
    __shared__ double redd[256];
    __shared__ double tot64[64];
    __shared__ __align__(16) float w1s[8][4];
    __shared__ __align__(16) float w2s[32][8];
    __shared__ __align__(16) float w3t[32][8];
    __shared__ float bb1[8], sc1[8], sh1[8];
    __shared__ float bb2[32], sc2[32], sh2[32];
    __shared__ float bb3[8];
    __shared__ float lred[4][16];

    {   // fin2 prologue from part2 [NB2][64]
        int st = t & 63, gr = t >> 6;   // 4 groups
        double acc = 0;
        for (int i = gr; i < NB2; i += 4) acc += (double)part2[(size_t)i * 64 + st];
        redd[t] = acc;
        __syncthreads();
        if (t < 64) tot64[t] = redd[t] + redd[t + 64] + redd[t + 128] + redd[t + 192];
        __syncthreads();
        if (t < 32) {
            double mean = tot64[t] / (double)NEL;
            double var = tot64[32 + t] / (double)NEL - mean * mean;
            float r = (float)(1.0 / sqrt(var + 1e-5));
            float sc = g2[t] * r;
            float sh = be2[t] - (float)mean * sc;
            sc2[t] = sc; sh2[t] = sh; bb2[t] = b2g[t];
            if (blockIdx.x == 0) { scsh2g[t] = sc; scsh2g[32 + t] = sh; }
        }
    }
    if (t < 32) { int o = t >> 2, c = t & 3; w1s[o][c] = (c < 3) ? w1g[o * 3 + c] : 0.f; }
    if (t < 8) { bb1[t] = b1g[t]; sc1[t] = scsh1g[t]; sh1[t] = scsh1g[8 + t]; bb3[t] = b3g[t]; }
    if (t < 256) { w2s[t >> 3][t & 7] = w2g[t]; w3t[t & 31][t >> 5] = w3g[t]; }
    __syncthreads();

    float ps[16];
#pragma unroll
    for (int s = 0; s < 16; ++s) ps[s] = 0.f;

    for (int chunk = blockIdx.x; chunk < NB_STAT; chunk += NB2) {
        int base = chunk * 1024 + t;
        bool ok[4];
        float y1[8][4];
#pragma unroll
        for (int e = 0; e < 4; ++e) {
            int i = base + (e << 8);
            ok[e] = (i < NEL);
            float f0 = 0.f, f1 = 0.f, f2 = 0.f;
            if (ok[e]) {
                int bq = i / VN; int v = i - bq * VN;
                f0 = s_arr[i]; f1 = mw_arr[i]; f2 = lik[v];
            }
#pragma unroll
            for (int o = 0; o < 8; ++o) {
                float4 wr = *(const float4*)&w1s[o][0];
                float z = bb1[o];
                z = fmaf(wr.x, f0, z); z = fmaf(wr.y, f1, z); z = fmaf(wr.z, f2, z);
                z = leaky1(z);
                y1[o][e] = fmaf(z, sc1[o], sh1[o]);
            }
        }
        float z3[8][4];
#pragma unroll
        for (int o3 = 0; o3 < 8; ++o3) {
            float bv = bb3[o3];
#pragma unroll
            for (int e = 0; e < 4; ++e) z3[o3][e] = bv;
        }
#pragma unroll 4
        for (int o = 0; o < 32; ++o) {
            float4 wa = *(const float4*)&w2s[o][0];
            float4 wb = *(const float4*)&w2s[o][4];
            float4 ua = *(const float4*)&w3t[o][0];
            float4 ub = *(const float4*)&w3t[o][4];
            float zb = bb2[o], sc = sc2[o], sh = sh2[o];
#pragma unroll
            for (int e = 0; e < 4; ++e) {
                float z = zb;
                z = fmaf(wa.x, y1[0][e], z); z = fmaf(wa.y, y1[1][e], z);
                z = fmaf(wa.z, y1[2][e], z); z = fmaf(wa.w, y1[3][e], z);
                z = fmaf(wb.x, y1[4][e], z); z = fmaf(wb.y, y1[5][e], z);
                z = fmaf(wb.z, y1[6][e], z); z = fmaf(wb.w, y1[7][e], z);
                z = leaky1(z);
                float y2 = fmaf(z, sc, sh);
                z3[0][e] = fmaf(ua.x, y2, z3[0][e]);
                z3[1][e] = fmaf(ua.y, y2, z3[1][e]);
                z3[2][e] = fmaf(ua.z, y2, z3[2][e]);
                z3[3][e] = fmaf(ua.w, y2, z3[3][e]);
                z3[4][e] = fmaf(ub.x, y2, z3[4][e]);
                z3[5][e] = fmaf(ub.y, y2, z3[5][e]);
                z3[6][e] = fmaf(ub.z, y2, z3[6][e]);
                z3[7][e] = fmaf(ub.w, y2, z3[7][e]);
            }
        }
#pragma unroll
        for (int e = 0; e < 4; ++e) {
            if (!ok[e]) continue;
#pragma unroll
            for (int o3 = 0; o3 < 8; ++o3) {
                float z = leaky1(z3[o3][e]);
                ps[o3] += z;
                ps[8 + o3] += z * z;
            }
        }
    }
    int lane = t & 63, w = t >> 6;
#pragma unroll
    for (int s = 0; s < 16; ++s) {
        float v2 = ps[s];
        v2 += __shfl_xor(v2, 1);  v2 += __shfl_xor(v2, 2);  v2 += __shfl_xor(v2, 4);
        v2 += __shfl_xor(v2, 8);  v2 += __shfl_xor(v2, 16); v2 += __shfl_xor(v2, 32);
        if (lane == 0) lred[w][s] = v2;
    }
    __syncthreads();
    if (t < 16) part3[blockIdx.x * 16 + t] = lred[0][t] + lred[1][t] + lred[2][t] + lred[3][t];
}

// ---------------- K7: output with FUSED fin3 prologue (r14, unchanged) ----------------
__global__ __launch_bounds__(256) void k_outf(
        const float* __restrict__ s_arr, const float* __restrict__ mw_arr,
        const float* __restrict__ lik,
        const float* __restrict__ w1g, const float* __restrict__ b1g,
        const float* __restrict__ scsh1g,
        const float* __restrict__ w2g, const float* __restrict__ b2g,
        const float* __restrict__ scsh2g,
        const float* __restrict__ w3g, const float* __restrict__ b3g,
        const float* __restrict__ part3,
        const float* __restrict__ g3, const float* __restrict__ be3,
        const float* __restrict__ w4g, const float* __restrict__ b4g,
        float* __restrict__ outp) {
    int t = threadIdx.x;
    __shared__ double redd[256];
    __shared__ __align__(16) float w1s[8][4];
    __shared__ __align__(16) float w2s[32][8];
    __shared__ __align__(16) float w3t[32][8];
    __shared__ float bb1[8], sc1[8], sh1[8];
    __shared__ float bb2[32], sc2[32], sh2[32];
    __shared__ float bb3[8], sc3[8], sh3[8], w4s[8];
    __shared__ float bb4s;

    {   // fin3 prologue from part3 [NB2][16]
        int st = t & 15, gr = t >> 4;
        double acc = 0;
        for (int i = gr; i < NB2; i += 16) acc += (double)part3[(size_t)i * 16 + st];
        redd[t] = acc;
        __syncthreads();
        if (t < 16) {
            double tot = redd[t];
            for (int g2i = 1; g2i < 16; ++g2i) tot += redd[t + g2i * 16];
            redd[t] = tot;
        }
        __syncthreads();
        if (t < 8) {
            double mean = redd[t] / (double)NEL;
            double var = redd[8 + t] / (double)NEL - mean * mean;
            float r = (float)(1.0 / sqrt(var + 1e-5));
            float sc = g3[t] * r;
            float sh = be3[t] - (float)mean * sc;
            sc3[t] = sc; sh3[t] = sh;
        }
    }
    if (t < 32) { int o = t >> 2, c = t & 3; w1s[o][c] = (c < 3) ? w1g[o * 3 + c] : 0.f; }
    if (t < 8) {
        bb1[t] = b1g[t]; sc1[t] = scsh1g[t]; sh1[t] = scsh1g[8 + t];
        bb3[t] = b3g[t]; w4s[t] = w4g[t];
    }
    if (t < 256) { w2s[t >> 3][t & 7] = w2g[t]; w3t[t & 31][t >> 5] = w3g[t]; }
    if (t < 32) { bb2[t] = b2g[t]; sc2[t] = scsh2g[t]; sh2[t] = scsh2g[32 + t]; }
    if (t == 0) bb4s = b4g[0];
    __syncthreads();

    int base = blockIdx.x * 1024 + t;
    bool ok[4];
    float y1[8][4];
#pragma unroll
    for (int e = 0; e < 4; ++e) {
        int i = base + (e << 8);
        ok[e] = (i < NEL);
        float f0 = 0.f, f1 = 0.f, f2 = 0.f;
        if (ok[e]) {
            int bq = i / VN; int v = i - bq * VN;
            f0 = s_arr[i]; f1 = mw_arr[i]; f2 = lik[v];
        }
#pragma unroll
        for (int o = 0; o < 8; ++o) {
            float4 wr = *(const float4*)&w1s[o][0];
            float z = bb1[o];
            z = fmaf(wr.x, f0, z); z = fmaf(wr.y, f1, z); z = fmaf(wr.z, f2, z);
            z = leaky1(z);
            y1[o][e] = fmaf(z, sc1[o], sh1[o]);
        }
    }
    float z3[8][4];
#pragma unroll
    for (int o3 = 0; o3 < 8; ++o3) {
        float bv = bb3[o3];
#pragma unroll
        for (int e = 0; e < 4; ++e) z3[o3][e] = bv;
    }
#pragma unroll 4
    for (int o = 0; o < 32; ++o) {
        float4 wa = *(const float4*)&w2s[o][0];
        float4 wb = *(const float4*)&w2s[o][4];
        float4 ua = *(const float4*)&w3t[o][0];
        float4 ub = *(const float4*)&w3t[o][4];
        float zb = bb2[o], sc = sc2[o], sh = sh2[o];
#pragma unroll
        for (int e = 0; e < 4; ++e) {
            float z = zb;
            z = fmaf(wa.x, y1[0][e], z); z = fmaf(wa.y, y1[1][e], z);
            z = fmaf(wa.z, y1[2][e], z); z = fmaf(wa.w, y1[3][e], z);
            z = fmaf(wb.x, y1[4][e], z); z = fmaf(wb.y, y1[5][e], z);
            z = fmaf(wb.z, y1[6][e], z); z = fmaf(wb.w, y1[7][e], z);
            z = leaky1(z);
            float y2 = fmaf(z, sc, sh);
            z3[0][e] = fmaf(ua.x, y2, z3[0][e]);
            z3[1][e] = fmaf(ua.y, y2, z3[1][e]);
            z3[2][e] = fmaf(ua.z, y2, z3[2][e]);
            z3[3][e] = fmaf(ua.w, y2, z3[3][e]);
            z3[4][e] = fmaf(ub.x, y2, z3[4][e]);
            z3[5][e] = fmaf(ub.y, y2, z3[5][e]);
            z3[6][e] = fmaf(ub.z, y2, z3[6][e]);
            z3[7][e] = fmaf(ub.w, y2, z3[7][e]);
        }
    }
#pragma unroll
    for (int e = 0; e < 4; ++e) {
        if (!ok[e]) continue;
        float oacc = bb4s;
#pragma unroll
        for (int o3 = 0; o3 < 8; ++o3) {
            float z = leaky1(z3[o3][e]);
            float y3 = fmaf(z, sc3[o3], sh3[o3]);
            oacc = fmaf(w4s[o3], y3, oacc);
        }
        outp[base + (e << 8)] = oacc;
    }
}

extern "C" void kernel_launch(void* const* d_in, const int* in_sizes, int n_in,
                              void* d_out, int out_size, void* d_ws, size_t ws_size,
                              hipStream_t stream) {
    const int*   hist = (const int*)d_in[0];
    const float* week = (const float*)d_in[1];
    const float* emb  = (const float*)d_in[2];
    const float* lik  = (const float*)d_in[3];
    const float* w1 = (const float*)d_in[4];
    const float* b1 = (const float*)d_in[5];
    const float* g1 = (const float*)d_in[6];
    const float* be1 = (const float*)d_in[7];
    const float* w2 = (const float*)d_in[8];
    const float* b2 = (const float*)d_in[9];
    const float* g2 = (const float*)d_in[10];
    const float* be2 = (const float*)d_in[11];
    const float* w3 = (const float*)d_in[12];
    const float* b3 = (const float*)d_in[13];
    const float* g3 = (const float*)d_in[14];
    const float* be3 = (const float*)d_in[15];
    const float* w4 = (const float*)d_in[16];
    const float* b4 = (const float*)d_in[17];
    float* outp = (float*)d_out;
    char* ws = (char*)d_ws;

    unsigned* cnt   = (unsigned*)(ws + OFF_CNT);
    unsigned* flags = (unsigned*)(ws + OFF_FLAG);
    float* rnorm = (float*)(ws + OFF_RNORM);
    double* rqd  = (double*)(ws + OFF_RQD);
    float* QgT   = (float*)(ws + OFF_QG);
    float* s_arr = (float*)(ws + OFF_S);
    float* mw    = (float*)(ws + OFF_MW);
    float* part1 = (float*)(ws + OFF_PART1);
    float* part2 = (float*)(ws + OFF_PART2);
    float* part3 = (float*)(ws + OFF_PART3);
    float* scsh1 = (float*)(ws + OFF_SCSH1);
    float* scsh2 = (float*)(ws + OFF_SCSH2);
    unsigned short* embh = (unsigned short*)(ws + OFF_EMBH);
    unsigned short* embl = (unsigned short*)(ws + OFF_EMBL);
    unsigned short* Qhp  = (unsigned short*)(ws + OFF_QH);
    unsigned short* Qlp  = (unsigned short*)(ws + OFF_QL);

    k_prep<<<NB_PREP, 256, 0, stream>>>(emb, hist, rnorm, embh, embl, QgT, rqd, Qhp, Qlp, cnt);
    k_sims<<<NBLK_SIMS, 512, 0, stream>>>(embh, embl, Qhp, Qlp, rnorm, week, s_arr, mw, cnt, flags);
    k_fixup<<<1024, 256, 0, stream>>>(emb, QgT, rqd, week, cnt, flags, mw);
    k_stat1<<<NB_STAT, 256, 0, stream>>>(s_arr, mw, lik, w1, b1, part1);
    k_stat2f<<<NB2, 256, 0, stream>>>(s_arr, mw, lik, w1, b1, part1, g1, be1, w2, b2, scsh1, part2);
    k_stat3f<<<NB2, 256, 0, stream>>>(s_arr, mw, lik, w1, b1, scsh1, part2, g2, be2, w2, b2, w3, b3, scsh2, part3);
    k_outf<<<NB_STAT, 256, 0, stream>>>(s_arr, mw, lik, w1, b1, scsh1, w2, b2, scsh2, w3, b3, part3, g3, be3, w4, b4, outp);
    (void)in_sizes; (void)n_in; (void)out_size; (void)ws_size;
}